// Round 8
// baseline (1441.574 us; speedup 1.0000x reference)
//
#include <hip/hip_runtime.h>
#include <hip/hip_bf16.h>

#define V_ 32000
#define D_ 256
#define H_ 512
#define B_ 32
#define T_ 64
#define NSL 8   // column slices per batch; GRU blocks = 32*NSL = 256

typedef __attribute__((ext_vector_type(8))) __bf16 bf16x8;
typedef __attribute__((ext_vector_type(4))) float f32x4;
typedef _Float16 f16x2 __attribute__((ext_vector_type(2)));
typedef unsigned int u32t;
typedef unsigned short u16t;
typedef unsigned long long u64t;

__device__ __forceinline__ u32t pack_h16(float a, float b) {
  union { _Float16 h; unsigned short u; } lo, hi;
  lo.h = (_Float16)a; hi.h = (_Float16)b;
  return (u32t)lo.u | ((u32t)hi.u << 16);
}

__device__ __forceinline__ float f16u_to_f(u16t u) {
  union { _Float16 h; unsigned short u; } x;
  x.u = u;
  return (float)x.h;
}

__device__ __forceinline__ float dot2(u32t w, u32t h, float acc) {
#if __has_builtin(__builtin_amdgcn_fdot2)
  return __builtin_amdgcn_fdot2(__builtin_bit_cast(f16x2, w),
                                __builtin_bit_cast(f16x2, h), acc, false);
#else
  f16x2 a = __builtin_bit_cast(f16x2, w);
  f16x2 b = __builtin_bit_cast(f16x2, h);
  return acc + (float)a.x * (float)b.x + (float)a.y * (float)b.y;
#endif
}

__device__ __forceinline__ void gld_lds16(const void* g, void* l) {
  __builtin_amdgcn_global_load_lds((const __attribute__((address_space(1))) void*)g,
                                   (__attribute__((address_space(3))) void*)l,
                                   16, 0, 0);
}

__device__ __forceinline__ u32t ld_rlx(const u32t* p) {
  return __hip_atomic_load(p, __ATOMIC_RELAXED, __HIP_MEMORY_SCOPE_AGENT);
}
__device__ __forceinline__ void st_rlx(u32t* p, u32t v) {
  __hip_atomic_store(p, v, __ATOMIC_RELAXED, __HIP_MEMORY_SCOPE_AGENT);
}

// ---------------- Wout [512][32000] f32 -> WoutT [32000][512] bf16 ----------------
__global__ __launch_bounds__(256) void k_transpose(const float* __restrict__ Wout,
                                                   __hip_bfloat16* __restrict__ WoutT) {
  __shared__ float tile[64][65];
  int v0 = blockIdx.x * 64;
  int h0 = blockIdx.y * 64;
  int tid = threadIdx.x;
#pragma unroll
  for (int i = 0; i < 16; ++i) {
    int idx = i * 256 + tid;
    int r = idx >> 6;
    int c = idx & 63;
    tile[r][c] = Wout[(size_t)(h0 + r) * V_ + v0 + c];
  }
  __syncthreads();
#pragma unroll
  for (int i = 0; i < 16; ++i) {
    int idx = i * 256 + tid;
    int rv = idx >> 6;
    int ch = idx & 63;
    WoutT[(size_t)(v0 + rv) * H_ + h0 + ch] = __float2bfloat16(tile[ch][rv]);
  }
}

// ---------------- weight packs (f16 pairs, per-thread register layouts) ----------
__global__ __launch_bounds__(256) void k_pack_g2(const float* __restrict__ Wg,
                                                 uint4* __restrict__ Wg2) {
  int gid = blockIdx.x * 256 + threadIdx.x;  // 0..65535
  int ks = gid & 3;
  int cq = (gid >> 2) & 127;
  int it = (gid >> 9) & 15;
  int s = gid >> 13;
  int j = (cq < 64) ? (s * 64 + cq) : (512 + s * 64 + (cq - 64));
  int k0 = ks * 128 + it * 8;
  uint4 v;
  v.x = pack_h16(Wg[(size_t)(256 + k0 + 0) * 1024 + j], Wg[(size_t)(256 + k0 + 1) * 1024 + j]);
  v.y = pack_h16(Wg[(size_t)(256 + k0 + 2) * 1024 + j], Wg[(size_t)(256 + k0 + 3) * 1024 + j]);
  v.z = pack_h16(Wg[(size_t)(256 + k0 + 4) * 1024 + j], Wg[(size_t)(256 + k0 + 5) * 1024 + j]);
  v.w = pack_h16(Wg[(size_t)(256 + k0 + 6) * 1024 + j], Wg[(size_t)(256 + k0 + 7) * 1024 + j]);
  Wg2[gid] = v;
}
__global__ __launch_bounds__(256) void k_pack_c2(const float* __restrict__ Wc,
                                                 uint4* __restrict__ Wc2) {
  int gid = blockIdx.x * 256 + threadIdx.x;  // 0..32767
  int ks8 = gid & 7;
  int cq2 = (gid >> 3) & 63;
  int it = (gid >> 9) & 7;
  int s = gid >> 12;
  int jc = s * 64 + cq2;
  int k0 = ks8 * 64 + it * 8;
  uint4 v;
  v.x = pack_h16(Wc[(size_t)(256 + k0 + 0) * 512 + jc], Wc[(size_t)(256 + k0 + 1) * 512 + jc]);
  v.y = pack_h16(Wc[(size_t)(256 + k0 + 2) * 512 + jc], Wc[(size_t)(256 + k0 + 3) * 512 + jc]);
  v.z = pack_h16(Wc[(size_t)(256 + k0 + 4) * 512 + jc], Wc[(size_t)(256 + k0 + 5) * 512 + jc]);
  v.w = pack_h16(Wc[(size_t)(256 + k0 + 6) * 512 + jc], Wc[(size_t)(256 + k0 + 7) * 512 + jc]);
  Wc2[gid] = v;
}

// ---------------- x-projection (gate): pre_g[n][1024] = x_n @ Wg[:256] + bg ----------
__global__ __launch_bounds__(256) void k_precompute_g(const int* __restrict__ widx,
                                                      const float* __restrict__ embW,
                                                      const float* __restrict__ Wg,
                                                      const float* __restrict__ bg,
                                                      float* __restrict__ pre_g) {
  __shared__ __align__(16) float x2[D_][8];
  __shared__ int wid[8];
  int tid = threadIdx.x;
  int n0 = blockIdx.x * 8;
  if (tid < 8) wid[tid] = widx[n0 + tid];
  __syncthreads();
#pragma unroll
  for (int i = 0; i < 8; ++i)
    x2[tid][i] = embW[(size_t)wid[i] * D_ + tid];
  __syncthreads();

  int J = blockIdx.y * 256 + tid;  // 0..1023
  float bias = bg[J];
  float acc[8];
#pragma unroll
  for (int i = 0; i < 8; ++i) acc[i] = bias;
  for (int d = 0; d < D_; ++d) {
    float4 xa = *(const float4*)&x2[d][0];
    float4 xb = *(const float4*)&x2[d][4];
    float w = Wg[(size_t)d * 1024 + J];
    acc[0] = fmaf(xa.x, w, acc[0]); acc[1] = fmaf(xa.y, w, acc[1]);
    acc[2] = fmaf(xa.z, w, acc[2]); acc[3] = fmaf(xa.w, w, acc[3]);
    acc[4] = fmaf(xb.x, w, acc[4]); acc[5] = fmaf(xb.y, w, acc[5]);
    acc[6] = fmaf(xb.z, w, acc[6]); acc[7] = fmaf(xb.w, w, acc[7]);
  }
#pragma unroll
  for (int i = 0; i < 8; ++i)
    pre_g[(size_t)(n0 + i) * 1024 + J] = acc[i];
}

// ---------------- x-projection (cand): pre_c[n][512] = bf16(x_n @ Wc[:256] + bc) -----
__global__ __launch_bounds__(256) void k_precompute_c(const int* __restrict__ widx,
                                                      const float* __restrict__ embW,
                                                      const float* __restrict__ Wc,
                                                      const float* __restrict__ bc,
                                                      __hip_bfloat16* __restrict__ pre_c) {
  __shared__ __align__(16) float x2[D_][8];
  __shared__ int wid[8];
  int tid = threadIdx.x;
  int n0 = blockIdx.x * 8;
  if (tid < 8) wid[tid] = widx[n0 + tid];
  __syncthreads();
#pragma unroll
  for (int i = 0; i < 8; ++i)
    x2[tid][i] = embW[(size_t)wid[i] * D_ + tid];
  __syncthreads();

  int Jc = blockIdx.y * 256 + tid;  // 0..511
  float bias = bc[Jc];
  float acc[8];
#pragma unroll
  for (int i = 0; i < 8; ++i) acc[i] = bias;
  for (int d = 0; d < D_; ++d) {
    float4 xa = *(const float4*)&x2[d][0];
    float4 xb = *(const float4*)&x2[d][4];
    float w = Wc[(size_t)d * 512 + Jc];
    acc[0] = fmaf(xa.x, w, acc[0]); acc[1] = fmaf(xa.y, w, acc[1]);
    acc[2] = fmaf(xa.z, w, acc[2]); acc[3] = fmaf(xa.w, w, acc[3]);
    acc[4] = fmaf(xb.x, w, acc[4]); acc[5] = fmaf(xb.y, w, acc[5]);
    acc[6] = fmaf(xb.z, w, acc[6]); acc[7] = fmaf(xb.w, w, acc[7]);
  }
#pragma unroll
  for (int i = 0; i < 8; ++i)
    pre_c[(size_t)(n0 + i) * 512 + Jc] = __float2bfloat16(acc[i]);
}

// ---------------- GRU init: tagged state buffers + zero AT tags ----------------
__global__ __launch_bounds__(256) void k_gru_init(const float* __restrict__ enc,
                                                  u32t* __restrict__ HBT,
                                                  u32t* __restrict__ RHT,
                                                  uint4* __restrict__ AT4) {
  int gid = blockIdx.x * 256 + threadIdx.x;  // 0..16383
  int b = gid >> 9, k = gid & 511;
  u32t hv = pack_h16(enc[b * H_ + k], 0.f) & 0xffffu;  // tag 0
  st_rlx(&HBT[gid], hv);
  st_rlx(&RHT[gid], 0xFFFF0000u);
  // zero AT (2048*512 u32 = 262144 uint4; 16 per thread)
  uint4 z = {0u, 0u, 0u, 0u};
#pragma unroll
  for (int i = 0; i < 16; ++i)
    AT4[(size_t)gid * 16 + i] = z;
}

// ---------------- fused GRU + projection ----------------
// Blocks 0..255: GRU v7 (tag-embedded exchange). A output: tagged u32 per element,
//   t-major rows: AT[(t*32+b)*512 + col] = {bf16 h_out, u16 tag=t+1}, st_rlx.
// Blocks 256..511: persistent 128x128 projection tiles in t-ascending order,
//   A reg-staged with per-element tag polling (agent loads), B via global_load_lds
//   with both-sides XOR swizzle, epilogue writes C[(b*64+t)*V + col] + bout.
// __launch_bounds__(512,4): VGPR<=128, LDS ~35KB -> any 2 blocks fit any CU ->
// all 512 blocks co-resident regardless of dispatch order (deadlock-free).
__global__ __launch_bounds__(512, 4) void k_fused(const int* __restrict__ num_words,
                                                  const uint4* __restrict__ Wg2,
                                                  const uint4* __restrict__ Wc2,
                                                  const float* __restrict__ pre_g,
                                                  const __hip_bfloat16* __restrict__ pre_c,
                                                  u32t* __restrict__ RHT,
                                                  u32t* __restrict__ HBT,
                                                  u32t* __restrict__ AT,
                                                  const __hip_bfloat16* __restrict__ BT,
                                                  const float* __restrict__ bout,
                                                  float* __restrict__ C) {
  __shared__ __align__(16) u32t h2_l[256];
  __shared__ __align__(16) u32t rh2_l[256];
  __shared__ float u_l[64];
  __shared__ __align__(16) char As[128 * 128];  // 128 rows x 64 bf16 (swizzled)
  __shared__ __align__(16) char Bs[128 * 128];
  int bid = blockIdx.x;
  int tid = threadIdx.x;

  if (bid < 256) {
    // ================= GRU =================
    int b = bid & 31;
    int s = bid >> 5;
    int nw = num_words[b];

    int cq = tid >> 2, ks = tid & 3;
    int j1 = (cq < 64) ? (s * 64 + cq) : (512 + s * 64 + (cq - 64));
    int cq2 = tid >> 3, ks8 = tid & 7;
    int jc = s * 64 + cq2;

    uint4 wg[16];
#pragma unroll
    for (int i = 0; i < 16; ++i) {
      int ii = (i + ks) & 15;
      wg[i] = Wg2[(((size_t)s * 16 + ii) * 128 + cq) * 4 + ks];
    }
    uint4 wc[8];
#pragma unroll
    for (int i = 0; i < 8; ++i) {
      int ii = (i + ks8) & 7;
      wc[i] = Wc2[(((size_t)s * 8 + ii) * 64 + cq2) * 8 + ks8];
    }

    u32t* HBp = HBT + (size_t)b * 512;
    u32t* RHp = RHT + (size_t)b * 512;
    bool pub1 = (ks == 0) && (cq < 64);
    bool ulane = (ks == 0) && (cq >= 64);
    bool pub2 = (ks8 == 0);

    for (int t = 0; t < T_; ++t) {
      float pg = pre_g[((size_t)b * T_ + t) * 1024 + j1];
      float pc = __bfloat162float(pre_c[((size_t)b * T_ + t) * 512 + jc]);

      __syncthreads();
      {
        u32t want = (u32t)t << 16;
        u32t v;
        do { v = ld_rlx(&HBp[tid]); } while ((v & 0xffff0000u) != want);
        ((volatile u16t*)h2_l)[tid] = (u16t)v;
      }
      __syncthreads();

      float a = 0.f;
      const uint4* h4 = (const uint4*)h2_l;
#pragma unroll
      for (int i = 0; i < 16; ++i) {
        int ii = (i + ks) & 15;
        uint4 hv = h4[ks * 16 + ii];
        a = dot2(wg[i].x, hv.x, a);
        a = dot2(wg[i].y, hv.y, a);
        a = dot2(wg[i].z, hv.z, a);
        a = dot2(wg[i].w, hv.w, a);
      }
      a += __shfl_xor(a, 1);
      a += __shfl_xor(a, 2);
      float gate = 1.f / (1.f + __expf(-(a + pg)));
      if (cq < 64) {
        float hh = f16u_to_f(((const u16t*)h2_l)[s * 64 + cq]);
        if (pub1)
          st_rlx(&RHp[s * 64 + cq],
                 (pack_h16(gate * hh, 0.f) & 0xffffu) | ((u32t)(t + 1) << 16));
      } else if (ulane) {
        u_l[cq - 64] = gate;
      }

      {
        u32t want = (u32t)(t + 1) << 16;
        u32t v;
        do { v = ld_rlx(&RHp[tid]); } while ((v & 0xffff0000u) != want);
        ((volatile u16t*)rh2_l)[tid] = (u16t)v;
      }
      __syncthreads();

      float a2 = 0.f;
      const uint4* r4 = (const uint4*)rh2_l;
#pragma unroll
      for (int i = 0; i < 8; ++i) {
        int ii = (i + ks8) & 7;
        uint4 rv = r4[ks8 * 8 + ii];
        a2 = dot2(wc[i].x, rv.x, a2);
        a2 = dot2(wc[i].y, rv.y, a2);
        a2 = dot2(wc[i].z, rv.z, a2);
        a2 = dot2(wc[i].w, rv.w, a2);
      }
      a2 += __shfl_xor(a2, 1);
      a2 += __shfl_xor(a2, 2);
      a2 += __shfl_xor(a2, 4);
      float cv = tanhf(a2 + pc);
      float uu = u_l[cq2];
      float hold = f16u_to_f(((const u16t*)h2_l)[jc]);
      float hn = uu * hold + (1.f - uu) * cv;
      bool live = t < nw;
      float hnext = live ? hn : hold;
      if (pub2) {
        st_rlx(&HBp[s * 64 + cq2],
               (pack_h16(hnext, 0.f) & 0xffffu) | ((u32t)(t + 1) << 16));
        u32t av = (u32t)__hip_bfloat16_raw(__float2bfloat16(live ? hn : 0.f)).x;
        st_rlx(&AT[((size_t)(t * 32 + b)) * 512 + jc], av | ((u32t)(t + 1) << 16));
      }
    }
  } else {
    // ================= projection (persistent, t-ascending tiles) =================
    int vid = bid - 256;
    int lane = tid & 63;
    int wave = tid >> 6;
    int wm = wave >> 1;   // 0..3 (row base wm*32)
    int wn = wave & 1;    // 0..1 (col base wn*64)
    int arow = tid >> 2;          // 0..127
    int akq = (tid & 3) << 4;     // k offset 0,16,32,48
    int aswz = (arow & 7) << 4;   // XOR swizzle for this row
    const char* Bb = (const char*)BT;

    for (int g4 = 0; g4 < 4; ++g4) {
#pragma unroll 1
      for (int j4 = 0; j4 < 4; ++j4) {
        int tau = g4 * 1024 + vid * 4 + j4;
        if (tau >= 4000) continue;
        int m = tau / 250;
        int n = tau - m * 250;
        u32t want = ((u32t)((m << 2) + (arow >> 5) + 1)) << 16;
        const u32t* Arow = AT + ((size_t)(m * 128 + arow)) * 512 + akq;

        f32x4 acc[2][4];
#pragma unroll
        for (int mi = 0; mi < 2; ++mi)
#pragma unroll
          for (int ni = 0; ni < 4; ++ni)
            acc[mi][ni] = (f32x4){0.f, 0.f, 0.f, 0.f};

        for (int ksx = 0; ksx < 8; ++ksx) {
          __syncthreads();  // prior MFMA reads done / prior tile done
          // ---- A stage: 16 tagged u32 in 2 batches of 8, poll until tags match ----
          const u32t* Asrc = Arow + ksx * 64;
#pragma unroll
          for (int half = 0; half < 2; ++half) {
            u32t v[8];
            bool ok;
            do {
              ok = true;
#pragma unroll
              for (int e = 0; e < 8; ++e) v[e] = ld_rlx(&Asrc[half * 8 + e]);
#pragma unroll
              for (int e = 0; e < 8; ++e) ok &= ((v[e] & 0xffff0000u) == want);
              if (!ok) __builtin_amdgcn_s_sleep(1);
            } while (!ok);
            uint4 p;
            p.x = (v[0] & 0xffffu) | (v[1] << 16);
            p.y = (v[2] & 0xffffu) | (v[3] << 16);
            p.z = (v[4] & 0xffffu) | (v[5] << 16);
            p.w = (v[6] & 0xffffu) | (v[7] << 16);
            int kb = (akq + half * 8) * 2;  // byte offset within 128B row
            *(uint4*)(As + arow * 128 + (kb ^ aswz)) = p;
          }
          // ---- B stage: gld_lds16, source pre-swizzled so LDS holds swizzled layout ----
#pragma unroll
          for (int inst = 0; inst < 2; ++inst) {
            int o = inst * 8192 + wave * 1024;
            int ol = o + lane * 16;
            int r = ol >> 7;
            int cb = ol & 127;
            int cbs = cb ^ ((r & 7) << 4);  // fetch the element that belongs at (r, cb)
            gld_lds16(Bb + ((size_t)(n * 128 + r) * 512 + ksx * 64) * 2 + cbs, Bs + o);
          }
          __syncthreads();
          // ---- MFMA ----
#pragma unroll
          for (int kk = 0; kk < 64; kk += 32) {
            int cbyte = kk * 2 + ((lane >> 4) << 4);
            bf16x8 af[2], bfr[4];
#pragma unroll
            for (int mi = 0; mi < 2; ++mi) {
              int row = wm * 32 + mi * 16 + (lane & 15);
              af[mi] = *(const bf16x8*)(As + row * 128 + (cbyte ^ ((row & 7) << 4)));
            }
#pragma unroll
            for (int ni = 0; ni < 4; ++ni) {
              int row = wn * 64 + ni * 16 + (lane & 15);
              bfr[ni] = *(const bf16x8*)(Bs + row * 128 + (cbyte ^ ((row & 7) << 4)));
            }
#pragma unroll
            for (int mi = 0; mi < 2; ++mi)
#pragma unroll
              for (int ni = 0; ni < 4; ++ni)
                acc[mi][ni] = __builtin_amdgcn_mfma_f32_16x16x32_bf16(af[mi], bfr[ni], acc[mi][ni], 0, 0, 0);
          }
        }
        // ---- epilogue: remap t-major row -> C[(b*64+t)] ----
#pragma unroll
        for (int ni = 0; ni < 4; ++ni) {
          int col = n * 128 + wn * 64 + ni * 16 + (lane & 15);
          float bb = bout[col];
#pragma unroll
          for (int mi = 0; mi < 2; ++mi) {
            int r0 = m * 128 + wm * 32 + mi * 16 + ((lane >> 4) << 2);
#pragma unroll
            for (int rr = 0; rr < 4; ++rr) {
              int r = r0 + rr;
              int tt = r >> 5;
              int bb2 = r & 31;
              C[((size_t)(bb2 * T_ + tt)) * V_ + col] = acc[mi][ni][rr] + bb;
            }
          }
        }
      }
    }
  }
}

extern "C" void kernel_launch(void* const* d_in, const int* in_sizes, int n_in,
                              void* d_out, int out_size, void* d_ws, size_t ws_size,
                              hipStream_t stream) {
  const int* widx = (const int*)d_in[0];
  const int* num_words = (const int*)d_in[1];
  const float* enc = (const float*)d_in[2];
  const float* embW = (const float*)d_in[3];
  const float* Wg = (const float*)d_in[4];
  const float* bg = (const float*)d_in[5];
  const float* Wc = (const float*)d_in[6];
  const float* bc = (const float*)d_in[7];
  const float* Wout = (const float*)d_in[8];
  const float* bout = (const float*)d_in[9];
  float* out = (float*)d_out;

  char* ws = (char*)d_ws;
  float* pre_g = (float*)(ws);                              // 8,388,608
  __hip_bfloat16* pre_c = (__hip_bfloat16*)(ws + 8388608);  // 2,097,152
  u32t* AT = (u32t*)(ws + 10485760);                        // 4,194,304 (tagged A)
  __hip_bfloat16* WoutT = (__hip_bfloat16*)(ws + 14680064); // 32,768,000
  uint4* Wg2 = (uint4*)(ws + 47448064);                     // 1,048,576
  uint4* Wc2 = (uint4*)(ws + 48496640);                     //   524,288
  u32t* RHT = (u32t*)(ws + 49020928);                       //    65,536
  u32t* HBT = (u32t*)(ws + 49086464);                       //    65,536

  hipLaunchKernelGGL(k_pack_g2, dim3(256), dim3(256), 0, stream, Wg, Wg2);
  hipLaunchKernelGGL(k_pack_c2, dim3(128), dim3(256), 0, stream, Wc, Wc2);
  hipLaunchKernelGGL(k_transpose, dim3(500, 8), dim3(256), 0, stream, Wout, WoutT);
  hipLaunchKernelGGL(k_precompute_g, dim3(256, 4), dim3(256), 0, stream,
                     widx, embW, Wg, bg, pre_g);
  hipLaunchKernelGGL(k_precompute_c, dim3(256, 2), dim3(256), 0, stream,
                     widx, embW, Wc, bc, pre_c);
  hipLaunchKernelGGL(k_gru_init, dim3(64), dim3(256), 0, stream, enc, HBT, RHT,
                     (uint4*)AT);
  hipLaunchKernelGGL(k_fused, dim3(512), dim3(512), 0, stream,
                     num_words, Wg2, Wc2, pre_g, pre_c, RHT, HBT, AT,
                     WoutT, bout, out);
}

// Round 9
// 883.052 us; speedup vs baseline: 1.6325x; 1.6325x over previous
//
#include <hip/hip_runtime.h>
#include <hip/hip_bf16.h>

#define V_ 32000
#define D_ 256
#define H_ 512
#define B_ 32
#define T_ 64
#define NSL 8   // column slices per batch; GRU blocks = 32*NSL = 256

typedef __attribute__((ext_vector_type(8))) __bf16 bf16x8;
typedef __attribute__((ext_vector_type(4))) float f32x4;
typedef _Float16 f16x2 __attribute__((ext_vector_type(2)));
typedef unsigned int u32t;
typedef unsigned short u16t;
typedef unsigned long long u64t;

__device__ __forceinline__ u32t pack_h16(float a, float b) {
  union { _Float16 h; unsigned short u; } lo, hi;
  lo.h = (_Float16)a; hi.h = (_Float16)b;
  return (u32t)lo.u | ((u32t)hi.u << 16);
}

__device__ __forceinline__ float f16u_to_f(u16t u) {
  union { _Float16 h; unsigned short u; } x;
  x.u = u;
  return (float)x.h;
}

__device__ __forceinline__ float dot2(u32t w, u32t h, float acc) {
#if __has_builtin(__builtin_amdgcn_fdot2)
  return __builtin_amdgcn_fdot2(__builtin_bit_cast(f16x2, w),
                                __builtin_bit_cast(f16x2, h), acc, false);
#else
  f16x2 a = __builtin_bit_cast(f16x2, w);
  f16x2 b = __builtin_bit_cast(f16x2, h);
  return acc + (float)a.x * (float)b.x + (float)a.y * (float)b.y;
#endif
}

__device__ __forceinline__ void gld_lds16(const void* g, void* l) {
  __builtin_amdgcn_global_load_lds((const __attribute__((address_space(1))) void*)g,
                                   (__attribute__((address_space(3))) void*)l,
                                   16, 0, 0);
}

__device__ __forceinline__ u32t ld_rlx(const u32t* p) {
  return __hip_atomic_load(p, __ATOMIC_RELAXED, __HIP_MEMORY_SCOPE_AGENT);
}
__device__ __forceinline__ void st_rlx(u32t* p, u32t v) {
  __hip_atomic_store(p, v, __ATOMIC_RELAXED, __HIP_MEMORY_SCOPE_AGENT);
}

// ---------------- Wout [512][32000] f32 -> WoutT [32000][512] bf16 ----------------
__global__ __launch_bounds__(256) void k_transpose(const float* __restrict__ Wout,
                                                   __hip_bfloat16* __restrict__ WoutT) {
  __shared__ float tile[64][65];
  int v0 = blockIdx.x * 64;
  int h0 = blockIdx.y * 64;
  int tid = threadIdx.x;
#pragma unroll
  for (int i = 0; i < 16; ++i) {
    int idx = i * 256 + tid;
    int r = idx >> 6;
    int c = idx & 63;
    tile[r][c] = Wout[(size_t)(h0 + r) * V_ + v0 + c];
  }
  __syncthreads();
#pragma unroll
  for (int i = 0; i < 16; ++i) {
    int idx = i * 256 + tid;
    int rv = idx >> 6;
    int ch = idx & 63;
    WoutT[(size_t)(v0 + rv) * H_ + h0 + ch] = __float2bfloat16(tile[ch][rv]);
  }
}

// ---------------- weight packs (f16 pairs, per-thread register layouts) ----------
__global__ __launch_bounds__(256) void k_pack_g2(const float* __restrict__ Wg,
                                                 uint4* __restrict__ Wg2) {
  int gid = blockIdx.x * 256 + threadIdx.x;  // 0..65535
  int ks = gid & 3;
  int cq = (gid >> 2) & 127;
  int it = (gid >> 9) & 15;
  int s = gid >> 13;
  int j = (cq < 64) ? (s * 64 + cq) : (512 + s * 64 + (cq - 64));
  int k0 = ks * 128 + it * 8;
  uint4 v;
  v.x = pack_h16(Wg[(size_t)(256 + k0 + 0) * 1024 + j], Wg[(size_t)(256 + k0 + 1) * 1024 + j]);
  v.y = pack_h16(Wg[(size_t)(256 + k0 + 2) * 1024 + j], Wg[(size_t)(256 + k0 + 3) * 1024 + j]);
  v.z = pack_h16(Wg[(size_t)(256 + k0 + 4) * 1024 + j], Wg[(size_t)(256 + k0 + 5) * 1024 + j]);
  v.w = pack_h16(Wg[(size_t)(256 + k0 + 6) * 1024 + j], Wg[(size_t)(256 + k0 + 7) * 1024 + j]);
  Wg2[gid] = v;
}
__global__ __launch_bounds__(256) void k_pack_c2(const float* __restrict__ Wc,
                                                 uint4* __restrict__ Wc2) {
  int gid = blockIdx.x * 256 + threadIdx.x;  // 0..32767
  int ks8 = gid & 7;
  int cq2 = (gid >> 3) & 63;
  int it = (gid >> 9) & 7;
  int s = gid >> 12;
  int jc = s * 64 + cq2;
  int k0 = ks8 * 64 + it * 8;
  uint4 v;
  v.x = pack_h16(Wc[(size_t)(256 + k0 + 0) * 512 + jc], Wc[(size_t)(256 + k0 + 1) * 512 + jc]);
  v.y = pack_h16(Wc[(size_t)(256 + k0 + 2) * 512 + jc], Wc[(size_t)(256 + k0 + 3) * 512 + jc]);
  v.z = pack_h16(Wc[(size_t)(256 + k0 + 4) * 512 + jc], Wc[(size_t)(256 + k0 + 5) * 512 + jc]);
  v.w = pack_h16(Wc[(size_t)(256 + k0 + 6) * 512 + jc], Wc[(size_t)(256 + k0 + 7) * 512 + jc]);
  Wc2[gid] = v;
}

// ---------------- x-projection (gate): pre_g[n][1024] = x_n @ Wg[:256] + bg ----------
__global__ __launch_bounds__(256) void k_precompute_g(const int* __restrict__ widx,
                                                      const float* __restrict__ embW,
                                                      const float* __restrict__ Wg,
                                                      const float* __restrict__ bg,
                                                      float* __restrict__ pre_g) {
  __shared__ __align__(16) float x2[D_][8];
  __shared__ int wid[8];
  int tid = threadIdx.x;
  int n0 = blockIdx.x * 8;
  if (tid < 8) wid[tid] = widx[n0 + tid];
  __syncthreads();
#pragma unroll
  for (int i = 0; i < 8; ++i)
    x2[tid][i] = embW[(size_t)wid[i] * D_ + tid];
  __syncthreads();

  int J = blockIdx.y * 256 + tid;  // 0..1023
  float bias = bg[J];
  float acc[8];
#pragma unroll
  for (int i = 0; i < 8; ++i) acc[i] = bias;
  for (int d = 0; d < D_; ++d) {
    float4 xa = *(const float4*)&x2[d][0];
    float4 xb = *(const float4*)&x2[d][4];
    float w = Wg[(size_t)d * 1024 + J];
    acc[0] = fmaf(xa.x, w, acc[0]); acc[1] = fmaf(xa.y, w, acc[1]);
    acc[2] = fmaf(xa.z, w, acc[2]); acc[3] = fmaf(xa.w, w, acc[3]);
    acc[4] = fmaf(xb.x, w, acc[4]); acc[5] = fmaf(xb.y, w, acc[5]);
    acc[6] = fmaf(xb.z, w, acc[6]); acc[7] = fmaf(xb.w, w, acc[7]);
  }
#pragma unroll
  for (int i = 0; i < 8; ++i)
    pre_g[(size_t)(n0 + i) * 1024 + J] = acc[i];
}

// ---------------- x-projection (cand): pre_c[n][512] = bf16(x_n @ Wc[:256] + bc) -----
__global__ __launch_bounds__(256) void k_precompute_c(const int* __restrict__ widx,
                                                      const float* __restrict__ embW,
                                                      const float* __restrict__ Wc,
                                                      const float* __restrict__ bc,
                                                      __hip_bfloat16* __restrict__ pre_c) {
  __shared__ __align__(16) float x2[D_][8];
  __shared__ int wid[8];
  int tid = threadIdx.x;
  int n0 = blockIdx.x * 8;
  if (tid < 8) wid[tid] = widx[n0 + tid];
  __syncthreads();
#pragma unroll
  for (int i = 0; i < 8; ++i)
    x2[tid][i] = embW[(size_t)wid[i] * D_ + tid];
  __syncthreads();

  int Jc = blockIdx.y * 256 + tid;  // 0..511
  float bias = bc[Jc];
  float acc[8];
#pragma unroll
  for (int i = 0; i < 8; ++i) acc[i] = bias;
  for (int d = 0; d < D_; ++d) {
    float4 xa = *(const float4*)&x2[d][0];
    float4 xb = *(const float4*)&x2[d][4];
    float w = Wc[(size_t)d * 512 + Jc];
    acc[0] = fmaf(xa.x, w, acc[0]); acc[1] = fmaf(xa.y, w, acc[1]);
    acc[2] = fmaf(xa.z, w, acc[2]); acc[3] = fmaf(xa.w, w, acc[3]);
    acc[4] = fmaf(xb.x, w, acc[4]); acc[5] = fmaf(xb.y, w, acc[5]);
    acc[6] = fmaf(xb.z, w, acc[6]); acc[7] = fmaf(xb.w, w, acc[7]);
  }
#pragma unroll
  for (int i = 0; i < 8; ++i)
    pre_c[(size_t)(n0 + i) * 512 + Jc] = __float2bfloat16(acc[i]);
}

// ---------------- GRU init: tagged state buffers + zero AT tags ----------------
__global__ __launch_bounds__(256) void k_gru_init(const float* __restrict__ enc,
                                                  u32t* __restrict__ HBT,
                                                  u32t* __restrict__ RHT,
                                                  uint4* __restrict__ AT4) {
  int gid = blockIdx.x * 256 + threadIdx.x;  // 0..16383
  int b = gid >> 9, k = gid & 511;
  u32t hv = pack_h16(enc[b * H_ + k], 0.f) & 0xffffu;  // tag 0
  st_rlx(&HBT[gid], hv);
  st_rlx(&RHT[gid], 0xFFFF0000u);
  uint4 z = {0u, 0u, 0u, 0u};
#pragma unroll
  for (int i = 0; i < 16; ++i)
    AT4[(size_t)gid * 16 + i] = z;
}

// ---------------- fused GRU + projection ----------------
// Blocks 0..255: GRU v7 (tag-embedded exchange), publishing tagged A rows t-major.
// Blocks 256..511: projection; block owns fixed n-tile (vid<250), sweeps m ascending
//   (t-order) polling tagged A; B via global_load_lds w/ both-sides XOR swizzle.
// __launch_bounds__(512, 2): 2 blocks/CU (this toolchain: arg2 = blocks/CU, evidence
// r2/r7/r8 VGPR caps 64/80/64) -> VGPR cap 128 (no GRU spill), all 512 co-resident.
__global__ __launch_bounds__(512, 2) void k_fused(const int* __restrict__ num_words,
                                                  const uint4* __restrict__ Wg2,
                                                  const uint4* __restrict__ Wc2,
                                                  const float* __restrict__ pre_g,
                                                  const __hip_bfloat16* __restrict__ pre_c,
                                                  u32t* __restrict__ RHT,
                                                  u32t* __restrict__ HBT,
                                                  u32t* __restrict__ AT,
                                                  const __hip_bfloat16* __restrict__ BT,
                                                  const float* __restrict__ bout,
                                                  float* __restrict__ C) {
  __shared__ __align__(16) u32t h2_l[256];
  __shared__ __align__(16) u32t rh2_l[256];
  __shared__ float u_l[64];
  __shared__ __align__(16) char As[128 * 128];  // 128 rows x 64 bf16 (swizzled)
  __shared__ __align__(16) char Bs[128 * 128];
  int bid = blockIdx.x;
  int tid = threadIdx.x;

  if (bid < 256) {
    // ================= GRU (v7, proven 193 us) =================
    int b = bid & 31;
    int s = bid >> 5;
    int nw = num_words[b];

    int cq = tid >> 2, ks = tid & 3;
    int j1 = (cq < 64) ? (s * 64 + cq) : (512 + s * 64 + (cq - 64));
    int cq2 = tid >> 3, ks8 = tid & 7;
    int jc = s * 64 + cq2;

    uint4 wg[16];
#pragma unroll
    for (int i = 0; i < 16; ++i) {
      int ii = (i + ks) & 15;
      wg[i] = Wg2[(((size_t)s * 16 + ii) * 128 + cq) * 4 + ks];
    }
    uint4 wc[8];
#pragma unroll
    for (int i = 0; i < 8; ++i) {
      int ii = (i + ks8) & 7;
      wc[i] = Wc2[(((size_t)s * 8 + ii) * 64 + cq2) * 8 + ks8];
    }

    u32t* HBp = HBT + (size_t)b * 512;
    u32t* RHp = RHT + (size_t)b * 512;
    bool pub1 = (ks == 0) && (cq < 64);
    bool ulane = (ks == 0) && (cq >= 64);
    bool pub2 = (ks8 == 0);

    for (int t = 0; t < T_; ++t) {
      float pg = pre_g[((size_t)b * T_ + t) * 1024 + j1];
      float pc = __bfloat162float(pre_c[((size_t)b * T_ + t) * 512 + jc]);

      __syncthreads();
      {
        u32t want = (u32t)t << 16;
        u32t v;
        do { v = ld_rlx(&HBp[tid]); } while ((v & 0xffff0000u) != want);
        ((volatile u16t*)h2_l)[tid] = (u16t)v;
      }
      __syncthreads();

      float a = 0.f;
      const uint4* h4 = (const uint4*)h2_l;
#pragma unroll
      for (int i = 0; i < 16; ++i) {
        int ii = (i + ks) & 15;
        uint4 hv = h4[ks * 16 + ii];
        a = dot2(wg[i].x, hv.x, a);
        a = dot2(wg[i].y, hv.y, a);
        a = dot2(wg[i].z, hv.z, a);
        a = dot2(wg[i].w, hv.w, a);
      }
      a += __shfl_xor(a, 1);
      a += __shfl_xor(a, 2);
      float gate = 1.f / (1.f + __expf(-(a + pg)));
      if (cq < 64) {
        float hh = f16u_to_f(((const u16t*)h2_l)[s * 64 + cq]);
        if (pub1)
          st_rlx(&RHp[s * 64 + cq],
                 (pack_h16(gate * hh, 0.f) & 0xffffu) | ((u32t)(t + 1) << 16));
      } else if (ulane) {
        u_l[cq - 64] = gate;
      }

      {
        u32t want = (u32t)(t + 1) << 16;
        u32t v;
        do { v = ld_rlx(&RHp[tid]); } while ((v & 0xffff0000u) != want);
        ((volatile u16t*)rh2_l)[tid] = (u16t)v;
      }
      __syncthreads();

      float a2 = 0.f;
      const uint4* r4 = (const uint4*)rh2_l;
#pragma unroll
      for (int i = 0; i < 8; ++i) {
        int ii = (i + ks8) & 7;
        uint4 rv = r4[ks8 * 8 + ii];
        a2 = dot2(wc[i].x, rv.x, a2);
        a2 = dot2(wc[i].y, rv.y, a2);
        a2 = dot2(wc[i].z, rv.z, a2);
        a2 = dot2(wc[i].w, rv.w, a2);
      }
      a2 += __shfl_xor(a2, 1);
      a2 += __shfl_xor(a2, 2);
      a2 += __shfl_xor(a2, 4);
      float cv = tanhf(a2 + pc);
      float uu = u_l[cq2];
      float hold = f16u_to_f(((const u16t*)h2_l)[jc]);
      float hn = uu * hold + (1.f - uu) * cv;
      bool live = t < nw;
      float hnext = live ? hn : hold;
      if (pub2) {
        st_rlx(&HBp[s * 64 + cq2],
               (pack_h16(hnext, 0.f) & 0xffffu) | ((u32t)(t + 1) << 16));
        u32t av = (u32t)__hip_bfloat16_raw(__float2bfloat16(live ? hn : 0.f)).x;
        st_rlx(&AT[((size_t)(t * 32 + b)) * 512 + jc], av | ((u32t)(t + 1) << 16));
      }
    }
  } else {
    // ================= projection: fixed n-tile, m ascending =================
    int n = bid - 256;          // n-tile 0..249 (250..255 idle)
    if (n < 250) {
      int lane = tid & 63;
      int wave = tid >> 6;
      int wm = wave >> 1;       // 0..3 (row base wm*32)
      int wn = wave & 1;        // 0..1 (col base wn*64)
      int arow = tid >> 2;      // 0..127
      int akq = (tid & 3) << 4; // k offset 0,16,32,48
      int aswz = (arow & 7) << 4;
      const char* Bb = (const char*)BT;

#pragma unroll 1
      for (int m = 0; m < 16; ++m) {
        u32t want = ((u32t)((m << 2) + (arow >> 5) + 1)) << 16;
        const u32t* Arow = AT + ((size_t)(m * 128 + arow)) * 512 + akq;

        f32x4 acc[2][4];
#pragma unroll
        for (int mi = 0; mi < 2; ++mi)
#pragma unroll
          for (int ni = 0; ni < 4; ++ni)
            acc[mi][ni] = (f32x4){0.f, 0.f, 0.f, 0.f};

        for (int ksx = 0; ksx < 8; ++ksx) {
          __syncthreads();  // prior MFMA reads done
          // ---- A stage: 16 tagged u32, poll until tags match ----
          const u32t* Asrc = Arow + ksx * 64;
#pragma unroll
          for (int half = 0; half < 2; ++half) {
            u32t v[8];
            bool ok;
            do {
              ok = true;
#pragma unroll
              for (int e = 0; e < 8; ++e) v[e] = ld_rlx(&Asrc[half * 8 + e]);
#pragma unroll
              for (int e = 0; e < 8; ++e) ok &= ((v[e] & 0xffff0000u) == want);
              if (!ok) __builtin_amdgcn_s_sleep(2);
            } while (!ok);
            uint4 p;
            p.x = (v[0] & 0xffffu) | (v[1] << 16);
            p.y = (v[2] & 0xffffu) | (v[3] << 16);
            p.z = (v[4] & 0xffffu) | (v[5] << 16);
            p.w = (v[6] & 0xffffu) | (v[7] << 16);
            int kb = (akq + half * 8) * 2;
            *(uint4*)(As + arow * 128 + (kb ^ aswz)) = p;
          }
          // ---- B stage: gld_lds16, pre-swizzled source ----
#pragma unroll
          for (int inst = 0; inst < 2; ++inst) {
            int o = inst * 8192 + wave * 1024;
            int ol = o + lane * 16;
            int r = ol >> 7;
            int cb = ol & 127;
            int cbs = cb ^ ((r & 7) << 4);
            gld_lds16(Bb + ((size_t)(n * 128 + r) * 512 + ksx * 64) * 2 + cbs, Bs + o);
          }
          __syncthreads();
          // ---- MFMA ----
#pragma unroll
          for (int kk = 0; kk < 64; kk += 32) {
            int cbyte = kk * 2 + ((lane >> 4) << 4);
            bf16x8 af[2], bfr[4];
#pragma unroll
            for (int mi = 0; mi < 2; ++mi) {
              int row = wm * 32 + mi * 16 + (lane & 15);
              af[mi] = *(const bf16x8*)(As + row * 128 + (cbyte ^ ((row & 7) << 4)));
            }
#pragma unroll
            for (int ni = 0; ni < 4; ++ni) {
              int row = wn * 64 + ni * 16 + (lane & 15);
              bfr[ni] = *(const bf16x8*)(Bs + row * 128 + (cbyte ^ ((row & 7) << 4)));
            }
#pragma unroll
            for (int mi = 0; mi < 2; ++mi)
#pragma unroll
              for (int ni = 0; ni < 4; ++ni)
                acc[mi][ni] = __builtin_amdgcn_mfma_f32_16x16x32_bf16(af[mi], bfr[ni], acc[mi][ni], 0, 0, 0);
          }
        }
        // ---- epilogue: remap t-major row -> C[(b*64+t)] ----
#pragma unroll
        for (int ni = 0; ni < 4; ++ni) {
          int col = n * 128 + wn * 64 + ni * 16 + (lane & 15);
          float bb = bout[col];
#pragma unroll
          for (int mi = 0; mi < 2; ++mi) {
            int r0 = m * 128 + wm * 32 + mi * 16 + ((lane >> 4) << 2);
#pragma unroll
            for (int rr = 0; rr < 4; ++rr) {
              int r = r0 + rr;
              int tt = r >> 5;
              int bb2 = r & 31;
              C[((size_t)(bb2 * T_ + tt)) * V_ + col] = acc[mi][ni][rr] + bb;
            }
          }
        }
      }
    }
  }
}

extern "C" void kernel_launch(void* const* d_in, const int* in_sizes, int n_in,
                              void* d_out, int out_size, void* d_ws, size_t ws_size,
                              hipStream_t stream) {
  const int* widx = (const int*)d_in[0];
  const int* num_words = (const int*)d_in[1];
  const float* enc = (const float*)d_in[2];
  const float* embW = (const float*)d_in[3];
  const float* Wg = (const float*)d_in[4];
  const float* bg = (const float*)d_in[5];
  const float* Wc = (const float*)d_in[6];
  const float* bc = (const float*)d_in[7];
  const float* Wout = (const float*)d_in[8];
  const float* bout = (const float*)d_in[9];
  float* out = (float*)d_out;

  char* ws = (char*)d_ws;
  float* pre_g = (float*)(ws);                              // 8,388,608
  __hip_bfloat16* pre_c = (__hip_bfloat16*)(ws + 8388608);  // 2,097,152
  u32t* AT = (u32t*)(ws + 10485760);                        // 4,194,304 (tagged A)
  __hip_bfloat16* WoutT = (__hip_bfloat16*)(ws + 14680064); // 32,768,000
  uint4* Wg2 = (uint4*)(ws + 47448064);                     // 1,048,576
  uint4* Wc2 = (uint4*)(ws + 48496640);                     //   524,288
  u32t* RHT = (u32t*)(ws + 49020928);                       //    65,536
  u32t* HBT = (u32t*)(ws + 49086464);                       //    65,536

  hipLaunchKernelGGL(k_pack_g2, dim3(256), dim3(256), 0, stream, Wg, Wg2);
  hipLaunchKernelGGL(k_pack_c2, dim3(128), dim3(256), 0, stream, Wc, Wc2);
  hipLaunchKernelGGL(k_transpose, dim3(500, 8), dim3(256), 0, stream, Wout, WoutT);
  hipLaunchKernelGGL(k_precompute_g, dim3(256, 4), dim3(256), 0, stream,
                     widx, embW, Wg, bg, pre_g);
  hipLaunchKernelGGL(k_precompute_c, dim3(256, 2), dim3(256), 0, stream,
                     widx, embW, Wc, bc, pre_c);
  hipLaunchKernelGGL(k_gru_init, dim3(64), dim3(256), 0, stream, enc, HBT, RHT,
                     (uint4*)AT);
  hipLaunchKernelGGL(k_fused, dim3(512), dim3(512), 0, stream,
                     num_words, Wg2, Wc2, pre_g, pre_c, RHT, HBT, AT,
                     WoutT, bout, out);
}

// Round 10
// 844.896 us; speedup vs baseline: 1.7062x; 1.0452x over previous
//
#include <hip/hip_runtime.h>
#include <hip/hip_bf16.h>

#define V_ 32000
#define D_ 256
#define H_ 512
#define B_ 32
#define T_ 64
#define NSL 8   // column slices per batch; GRU blocks = 32*NSL = 256

typedef __attribute__((ext_vector_type(8))) __bf16 bf16x8;
typedef __attribute__((ext_vector_type(4))) float f32x4;
typedef _Float16 f16x2 __attribute__((ext_vector_type(2)));
typedef unsigned int u32t;
typedef unsigned short u16t;
typedef unsigned long long u64t;

__device__ __forceinline__ u32t pack_h16(float a, float b) {
  union { _Float16 h; unsigned short u; } lo, hi;
  lo.h = (_Float16)a; hi.h = (_Float16)b;
  return (u32t)lo.u | ((u32t)hi.u << 16);
}

__device__ __forceinline__ float f16u_to_f(u16t u) {
  union { _Float16 h; unsigned short u; } x;
  x.u = u;
  return (float)x.h;
}

__device__ __forceinline__ float dot2(u32t w, u32t h, float acc) {
#if __has_builtin(__builtin_amdgcn_fdot2)
  return __builtin_amdgcn_fdot2(__builtin_bit_cast(f16x2, w),
                                __builtin_bit_cast(f16x2, h), acc, false);
#else
  f16x2 a = __builtin_bit_cast(f16x2, w);
  f16x2 b = __builtin_bit_cast(f16x2, h);
  return acc + (float)a.x * (float)b.x + (float)a.y * (float)b.y;
#endif
}

__device__ __forceinline__ void gld_lds16(const void* g, void* l) {
  __builtin_amdgcn_global_load_lds((const __attribute__((address_space(1))) void*)g,
                                   (__attribute__((address_space(3))) void*)l,
                                   16, 0, 0);
}

__device__ __forceinline__ u32t ld_rlx(const u32t* p) {
  return __hip_atomic_load(p, __ATOMIC_RELAXED, __HIP_MEMORY_SCOPE_AGENT);
}
__device__ __forceinline__ void st_rlx(u32t* p, u32t v) {
  __hip_atomic_store(p, v, __ATOMIC_RELAXED, __HIP_MEMORY_SCOPE_AGENT);
}

// ---------------- Wout [512][32000] f32 -> WoutT [32000][512] bf16 ----------------
__global__ __launch_bounds__(256) void k_transpose(const float* __restrict__ Wout,
                                                   __hip_bfloat16* __restrict__ WoutT) {
  __shared__ float tile[64][65];
  int v0 = blockIdx.x * 64;
  int h0 = blockIdx.y * 64;
  int tid = threadIdx.x;
#pragma unroll
  for (int i = 0; i < 16; ++i) {
    int idx = i * 256 + tid;
    int r = idx >> 6;
    int c = idx & 63;
    tile[r][c] = Wout[(size_t)(h0 + r) * V_ + v0 + c];
  }
  __syncthreads();
#pragma unroll
  for (int i = 0; i < 16; ++i) {
    int idx = i * 256 + tid;
    int rv = idx >> 6;
    int ch = idx & 63;
    WoutT[(size_t)(v0 + rv) * H_ + h0 + ch] = __float2bfloat16(tile[ch][rv]);
  }
}

// ---------------- weight packs (f16 pairs, per-thread register layouts) ----------
__global__ __launch_bounds__(256) void k_pack_g2(const float* __restrict__ Wg,
                                                 uint4* __restrict__ Wg2) {
  int gid = blockIdx.x * 256 + threadIdx.x;  // 0..65535
  int ks = gid & 3;
  int cq = (gid >> 2) & 127;
  int it = (gid >> 9) & 15;
  int s = gid >> 13;
  int j = (cq < 64) ? (s * 64 + cq) : (512 + s * 64 + (cq - 64));
  int k0 = ks * 128 + it * 8;
  uint4 v;
  v.x = pack_h16(Wg[(size_t)(256 + k0 + 0) * 1024 + j], Wg[(size_t)(256 + k0 + 1) * 1024 + j]);
  v.y = pack_h16(Wg[(size_t)(256 + k0 + 2) * 1024 + j], Wg[(size_t)(256 + k0 + 3) * 1024 + j]);
  v.z = pack_h16(Wg[(size_t)(256 + k0 + 4) * 1024 + j], Wg[(size_t)(256 + k0 + 5) * 1024 + j]);
  v.w = pack_h16(Wg[(size_t)(256 + k0 + 6) * 1024 + j], Wg[(size_t)(256 + k0 + 7) * 1024 + j]);
  Wg2[gid] = v;
}
__global__ __launch_bounds__(256) void k_pack_c2(const float* __restrict__ Wc,
                                                 uint4* __restrict__ Wc2) {
  int gid = blockIdx.x * 256 + threadIdx.x;  // 0..32767
  int ks8 = gid & 7;
  int cq2 = (gid >> 3) & 63;
  int it = (gid >> 9) & 7;
  int s = gid >> 12;
  int jc = s * 64 + cq2;
  int k0 = ks8 * 64 + it * 8;
  uint4 v;
  v.x = pack_h16(Wc[(size_t)(256 + k0 + 0) * 512 + jc], Wc[(size_t)(256 + k0 + 1) * 512 + jc]);
  v.y = pack_h16(Wc[(size_t)(256 + k0 + 2) * 512 + jc], Wc[(size_t)(256 + k0 + 3) * 512 + jc]);
  v.z = pack_h16(Wc[(size_t)(256 + k0 + 4) * 512 + jc], Wc[(size_t)(256 + k0 + 5) * 512 + jc]);
  v.w = pack_h16(Wc[(size_t)(256 + k0 + 6) * 512 + jc], Wc[(size_t)(256 + k0 + 7) * 512 + jc]);
  Wc2[gid] = v;
}

// ---------------- x-projection (gate): pre_g[n][1024] = x_n @ Wg[:256] + bg ----------
__global__ __launch_bounds__(256) void k_precompute_g(const int* __restrict__ widx,
                                                      const float* __restrict__ embW,
                                                      const float* __restrict__ Wg,
                                                      const float* __restrict__ bg,
                                                      float* __restrict__ pre_g) {
  __shared__ __align__(16) float x2[D_][8];
  __shared__ int wid[8];
  int tid = threadIdx.x;
  int n0 = blockIdx.x * 8;
  if (tid < 8) wid[tid] = widx[n0 + tid];
  __syncthreads();
#pragma unroll
  for (int i = 0; i < 8; ++i)
    x2[tid][i] = embW[(size_t)wid[i] * D_ + tid];
  __syncthreads();

  int J = blockIdx.y * 256 + tid;  // 0..1023
  float bias = bg[J];
  float acc[8];
#pragma unroll
  for (int i = 0; i < 8; ++i) acc[i] = bias;
  for (int d = 0; d < D_; ++d) {
    float4 xa = *(const float4*)&x2[d][0];
    float4 xb = *(const float4*)&x2[d][4];
    float w = Wg[(size_t)d * 1024 + J];
    acc[0] = fmaf(xa.x, w, acc[0]); acc[1] = fmaf(xa.y, w, acc[1]);
    acc[2] = fmaf(xa.z, w, acc[2]); acc[3] = fmaf(xa.w, w, acc[3]);
    acc[4] = fmaf(xb.x, w, acc[4]); acc[5] = fmaf(xb.y, w, acc[5]);
    acc[6] = fmaf(xb.z, w, acc[6]); acc[7] = fmaf(xb.w, w, acc[7]);
  }
#pragma unroll
  for (int i = 0; i < 8; ++i)
    pre_g[(size_t)(n0 + i) * 1024 + J] = acc[i];
}

// ---------------- x-projection (cand): pre_c[n][512] = bf16(x_n @ Wc[:256] + bc) -----
__global__ __launch_bounds__(256) void k_precompute_c(const int* __restrict__ widx,
                                                      const float* __restrict__ embW,
                                                      const float* __restrict__ Wc,
                                                      const float* __restrict__ bc,
                                                      __hip_bfloat16* __restrict__ pre_c) {
  __shared__ __align__(16) float x2[D_][8];
  __shared__ int wid[8];
  int tid = threadIdx.x;
  int n0 = blockIdx.x * 8;
  if (tid < 8) wid[tid] = widx[n0 + tid];
  __syncthreads();
#pragma unroll
  for (int i = 0; i < 8; ++i)
    x2[tid][i] = embW[(size_t)wid[i] * D_ + tid];
  __syncthreads();

  int Jc = blockIdx.y * 256 + tid;  // 0..511
  float bias = bc[Jc];
  float acc[8];
#pragma unroll
  for (int i = 0; i < 8; ++i) acc[i] = bias;
  for (int d = 0; d < D_; ++d) {
    float4 xa = *(const float4*)&x2[d][0];
    float4 xb = *(const float4*)&x2[d][4];
    float w = Wc[(size_t)d * 512 + Jc];
    acc[0] = fmaf(xa.x, w, acc[0]); acc[1] = fmaf(xa.y, w, acc[1]);
    acc[2] = fmaf(xa.z, w, acc[2]); acc[3] = fmaf(xa.w, w, acc[3]);
    acc[4] = fmaf(xb.x, w, acc[4]); acc[5] = fmaf(xb.y, w, acc[5]);
    acc[6] = fmaf(xb.z, w, acc[6]); acc[7] = fmaf(xb.w, w, acc[7]);
  }
#pragma unroll
  for (int i = 0; i < 8; ++i)
    pre_c[(size_t)(n0 + i) * 512 + Jc] = __float2bfloat16(acc[i]);
}

// ---------------- GRU init: tagged state buffers + zero AT tags + pool reset --------
__global__ __launch_bounds__(256) void k_gru_init(const float* __restrict__ enc,
                                                  u32t* __restrict__ HBT,
                                                  u32t* __restrict__ RHT,
                                                  uint4* __restrict__ AT4,
                                                  u32t* __restrict__ pool) {
  int gid = blockIdx.x * 256 + threadIdx.x;  // 0..16383
  int b = gid >> 9, k = gid & 511;
  u32t hv = pack_h16(enc[b * H_ + k], 0.f) & 0xffffu;  // tag 0
  st_rlx(&HBT[gid], hv);
  st_rlx(&RHT[gid], 0xFFFF0000u);
  if (gid == 0) st_rlx(pool, 0u);
  uint4 z = {0u, 0u, 0u, 0u};
#pragma unroll
  for (int i = 0; i < 16; ++i)
    AT4[(size_t)gid * 16 + i] = z;
}

// ---------------- proj helpers ----------------
__device__ __forceinline__ void proj_issue_B(const char* Bnt, int ks, char* Bbuf,
                                             int lane, int wave) {
#pragma unroll
  for (int inst = 0; inst < 2; ++inst) {
    int o = inst * 8192 + wave * 1024;
    int ol = o + lane * 16;
    int r = ol >> 7;
    int cb = ol & 127;
    int cbs = cb ^ ((r & 7) << 4);
    gld_lds16(Bnt + (size_t)r * 1024 + ks * 128 + cbs, Bbuf + o);
  }
}

__device__ __forceinline__ void proj_stage_A(const u32t* Arow, u32t want, int ks,
                                             char* Abuf, int arow, int akq, int aswz) {
  const u32t* Asrc = Arow + ks * 64;
#pragma unroll
  for (int half = 0; half < 2; ++half) {
    u32t v[8];
    bool ok;
    do {
      ok = true;
#pragma unroll
      for (int e = 0; e < 8; ++e) v[e] = ld_rlx(&Asrc[half * 8 + e]);
#pragma unroll
      for (int e = 0; e < 8; ++e) ok &= ((v[e] & 0xffff0000u) == want);
      if (!ok) __builtin_amdgcn_s_sleep(4);
    } while (!ok);
    uint4 p;
    p.x = (v[0] & 0xffffu) | (v[1] << 16);
    p.y = (v[2] & 0xffffu) | (v[3] << 16);
    p.z = (v[4] & 0xffffu) | (v[5] << 16);
    p.w = (v[6] & 0xffffu) | (v[7] << 16);
    int kb = (akq + half * 8) * 2;
    *(uint4*)(Abuf + arow * 128 + (kb ^ aswz)) = p;
  }
}

// ---------------- fused GRU + projection (work-stealing pool) ----------------
// Blocks 0..255: GRU v7 (tag-embedded exchange) publishing tagged A t-major, then
// they JOIN the projection pool. Blocks 256..511: projection pool from the start.
// Pool: global atomic counter over tau = m*250+n (m ascending = t-order, so the
// frontier follows A availability). Per tile: double-buffered As/Bs (2x16KB each),
// B(ks+1) issued before MFMA(ks) so its latency hides under A-stage+MFMA; C written
// with nontemporal stores so the 262MB stream does not evict WoutT from L3.
// __launch_bounds__(512, 2): 2 blocks/CU (this toolchain: arg2 = blocks/CU; evidence
// r2/r7/r8 VGPR caps 64/80/64) -> 128-VGPR cap (no GRU spill), 512 co-resident.
__global__ __launch_bounds__(512, 2) void k_fused(const int* __restrict__ num_words,
                                                  const uint4* __restrict__ Wg2,
                                                  const uint4* __restrict__ Wc2,
                                                  const float* __restrict__ pre_g,
                                                  const __hip_bfloat16* __restrict__ pre_c,
                                                  u32t* __restrict__ RHT,
                                                  u32t* __restrict__ HBT,
                                                  u32t* __restrict__ AT,
                                                  const __hip_bfloat16* __restrict__ BT,
                                                  const float* __restrict__ bout,
                                                  float* __restrict__ C,
                                                  u32t* __restrict__ pool) {
  __shared__ __align__(16) u32t h2_l[256];
  __shared__ __align__(16) u32t rh2_l[256];
  __shared__ float u_l[64];
  __shared__ __align__(16) char As[2][128 * 128];
  __shared__ __align__(16) char Bs[2][128 * 128];
  __shared__ int tau_sh;
  int bid = blockIdx.x;
  int tid = threadIdx.x;

  if (bid < 256) {
    // ================= GRU (v7 structure, proven 193 us standalone) =================
    int b = bid & 31;
    int s = bid >> 5;
    int nw = num_words[b];

    int cq = tid >> 2, ks = tid & 3;
    int j1 = (cq < 64) ? (s * 64 + cq) : (512 + s * 64 + (cq - 64));
    int cq2 = tid >> 3, ks8 = tid & 7;
    int jc = s * 64 + cq2;

    uint4 wg[16];
#pragma unroll
    for (int i = 0; i < 16; ++i) {
      int ii = (i + ks) & 15;
      wg[i] = Wg2[(((size_t)s * 16 + ii) * 128 + cq) * 4 + ks];
    }
    uint4 wc[8];
#pragma unroll
    for (int i = 0; i < 8; ++i) {
      int ii = (i + ks8) & 7;
      wc[i] = Wc2[(((size_t)s * 8 + ii) * 64 + cq2) * 8 + ks8];
    }

    u32t* HBp = HBT + (size_t)b * 512;
    u32t* RHp = RHT + (size_t)b * 512;
    bool pub1 = (ks == 0) && (cq < 64);
    bool ulane = (ks == 0) && (cq >= 64);
    bool pub2 = (ks8 == 0);

    for (int t = 0; t < T_; ++t) {
      float pg = pre_g[((size_t)b * T_ + t) * 1024 + j1];
      float pc = __bfloat162float(pre_c[((size_t)b * T_ + t) * 512 + jc]);

      __syncthreads();
      {
        u32t want = (u32t)t << 16;
        u32t v;
        do { v = ld_rlx(&HBp[tid]); } while ((v & 0xffff0000u) != want);
        ((volatile u16t*)h2_l)[tid] = (u16t)v;
      }
      __syncthreads();

      float a = 0.f;
      const uint4* h4 = (const uint4*)h2_l;
#pragma unroll
      for (int i = 0; i < 16; ++i) {
        int ii = (i + ks) & 15;
        uint4 hv = h4[ks * 16 + ii];
        a = dot2(wg[i].x, hv.x, a);
        a = dot2(wg[i].y, hv.y, a);
        a = dot2(wg[i].z, hv.z, a);
        a = dot2(wg[i].w, hv.w, a);
      }
      a += __shfl_xor(a, 1);
      a += __shfl_xor(a, 2);
      float gate = 1.f / (1.f + __expf(-(a + pg)));
      if (cq < 64) {
        float hh = f16u_to_f(((const u16t*)h2_l)[s * 64 + cq]);
        if (pub1)
          st_rlx(&RHp[s * 64 + cq],
                 (pack_h16(gate * hh, 0.f) & 0xffffu) | ((u32t)(t + 1) << 16));
      } else if (ulane) {
        u_l[cq - 64] = gate;
      }

      {
        u32t want = (u32t)(t + 1) << 16;
        u32t v;
        do { v = ld_rlx(&RHp[tid]); } while ((v & 0xffff0000u) != want);
        ((volatile u16t*)rh2_l)[tid] = (u16t)v;
      }
      __syncthreads();

      float a2 = 0.f;
      const uint4* r4 = (const uint4*)rh2_l;
#pragma unroll
      for (int i = 0; i < 8; ++i) {
        int ii = (i + ks8) & 7;
        uint4 rv = r4[ks8 * 8 + ii];
        a2 = dot2(wc[i].x, rv.x, a2);
        a2 = dot2(wc[i].y, rv.y, a2);
        a2 = dot2(wc[i].z, rv.z, a2);
        a2 = dot2(wc[i].w, rv.w, a2);
      }
      a2 += __shfl_xor(a2, 1);
      a2 += __shfl_xor(a2, 2);
      a2 += __shfl_xor(a2, 4);
      float cv = tanhf(a2 + pc);
      float uu = u_l[cq2];
      float hold = f16u_to_f(((const u16t*)h2_l)[jc]);
      float hn = uu * hold + (1.f - uu) * cv;
      bool live = t < nw;
      float hnext = live ? hn : hold;
      if (pub2) {
        st_rlx(&HBp[s * 64 + cq2],
               (pack_h16(hnext, 0.f) & 0xffffu) | ((u32t)(t + 1) << 16));
        u32t av = (u32t)__hip_bfloat16_raw(__float2bfloat16(live ? hn : 0.f)).x;
        st_rlx(&AT[((size_t)(t * 32 + b)) * 512 + jc], av | ((u32t)(t + 1) << 16));
      }
    }
  }

  // ================= projection pool (all blocks; GRU blocks join when done) ========
  {
    int lane = tid & 63;
    int wave = tid >> 6;
    int wm = wave >> 1;       // 0..3 (row base wm*32)
    int wn = wave & 1;        // 0..1 (col base wn*64)
    int arow = tid >> 2;      // 0..127
    int akq = (tid & 3) << 4; // k offset 0,16,32,48
    int aswz = (arow & 7) << 4;
    const char* Bb = (const char*)BT;

    for (;;) {
      __syncthreads();  // protect tau_sh + As/Bs reuse across tiles
      if (tid == 0)
        tau_sh = (int)__hip_atomic_fetch_add(pool, 1u, __ATOMIC_RELAXED,
                                             __HIP_MEMORY_SCOPE_AGENT);
      __syncthreads();
      int tau = tau_sh;
      if (tau >= 4000) break;
      int m = tau / 250;
      int n = tau - m * 250;
      const char* Bnt = Bb + (size_t)(n * 128) * 1024;  // B row stride 512*2 B
      u32t want = ((u32t)((m << 2) + (arow >> 5) + 1)) << 16;
      const u32t* Arow = AT + ((size_t)(m * 128 + arow)) * 512 + akq;

      f32x4 acc[2][4];
#pragma unroll
      for (int mi = 0; mi < 2; ++mi)
#pragma unroll
        for (int ni = 0; ni < 4; ++ni)
          acc[mi][ni] = (f32x4){0.f, 0.f, 0.f, 0.f};

      proj_issue_B(Bnt, 0, Bs[0], lane, wave);
      proj_stage_A(Arow, want, 0, As[0], arow, akq, aswz);

      for (int ksx = 0; ksx < 8; ++ksx) {
        char* Acur = As[ksx & 1];
        char* Bcur = Bs[ksx & 1];
        __syncthreads();  // drains vmcnt: B(ksx) in LDS; lgkm: A(ksx) writes visible
        if (ksx < 7) {
          proj_issue_B(Bnt, ksx + 1, Bs[(ksx + 1) & 1], lane, wave);
          proj_stage_A(Arow, want, ksx + 1, As[(ksx + 1) & 1], arow, akq, aswz);
        }
        // ---- MFMA(ksx): B(ksx+1) stays in flight under this compute ----
#pragma unroll
        for (int kk = 0; kk < 64; kk += 32) {
          int cbyte = kk * 2 + ((lane >> 4) << 4);
          bf16x8 af[2], bfr[4];
#pragma unroll
          for (int mi = 0; mi < 2; ++mi) {
            int row = wm * 32 + mi * 16 + (lane & 15);
            af[mi] = *(const bf16x8*)(Acur + row * 128 + (cbyte ^ ((row & 7) << 4)));
          }
#pragma unroll
          for (int ni = 0; ni < 4; ++ni) {
            int row = wn * 64 + ni * 16 + (lane & 15);
            bfr[ni] = *(const bf16x8*)(Bcur + row * 128 + (cbyte ^ ((row & 7) << 4)));
          }
#pragma unroll
          for (int mi = 0; mi < 2; ++mi)
#pragma unroll
            for (int ni = 0; ni < 4; ++ni)
              acc[mi][ni] = __builtin_amdgcn_mfma_f32_16x16x32_bf16(af[mi], bfr[ni], acc[mi][ni], 0, 0, 0);
        }
      }
      // ---- epilogue: remap t-major row -> C[(b*64+t)], nontemporal (no L3 evict) ----
#pragma unroll
      for (int ni = 0; ni < 4; ++ni) {
        int col = n * 128 + wn * 64 + ni * 16 + (lane & 15);
        float bb = bout[col];
#pragma unroll
        for (int mi = 0; mi < 2; ++mi) {
          int r0 = m * 128 + wm * 32 + mi * 16 + ((lane >> 4) << 2);
#pragma unroll
          for (int rr = 0; rr < 4; ++rr) {
            int r = r0 + rr;
            int tt = r >> 5;
            int bb2 = r & 31;
            __builtin_nontemporal_store(acc[mi][ni][rr] + bb,
                                        &C[((size_t)(bb2 * T_ + tt)) * V_ + col]);
          }
        }
      }
    }
  }
}

extern "C" void kernel_launch(void* const* d_in, const int* in_sizes, int n_in,
                              void* d_out, int out_size, void* d_ws, size_t ws_size,
                              hipStream_t stream) {
  const int* widx = (const int*)d_in[0];
  const int* num_words = (const int*)d_in[1];
  const float* enc = (const float*)d_in[2];
  const float* embW = (const float*)d_in[3];
  const float* Wg = (const float*)d_in[4];
  const float* bg = (const float*)d_in[5];
  const float* Wc = (const float*)d_in[6];
  const float* bc = (const float*)d_in[7];
  const float* Wout = (const float*)d_in[8];
  const float* bout = (const float*)d_in[9];
  float* out = (float*)d_out;

  char* ws = (char*)d_ws;
  float* pre_g = (float*)(ws);                              // 8,388,608
  __hip_bfloat16* pre_c = (__hip_bfloat16*)(ws + 8388608);  // 2,097,152
  u32t* AT = (u32t*)(ws + 10485760);                        // 4,194,304 (tagged A)
  __hip_bfloat16* WoutT = (__hip_bfloat16*)(ws + 14680064); // 32,768,000
  uint4* Wg2 = (uint4*)(ws + 47448064);                     // 1,048,576
  uint4* Wc2 = (uint4*)(ws + 48496640);                     //   524,288
  u32t* RHT = (u32t*)(ws + 49020928);                       //    65,536
  u32t* HBT = (u32t*)(ws + 49086464);                       //    65,536
  u32t* pool = (u32t*)(ws + 49152000);                      //       256

  hipLaunchKernelGGL(k_pack_g2, dim3(256), dim3(256), 0, stream, Wg, Wg2);
  hipLaunchKernelGGL(k_pack_c2, dim3(128), dim3(256), 0, stream, Wc, Wc2);
  hipLaunchKernelGGL(k_transpose, dim3(500, 8), dim3(256), 0, stream, Wout, WoutT);
  hipLaunchKernelGGL(k_precompute_g, dim3(256, 4), dim3(256), 0, stream,
                     widx, embW, Wg, bg, pre_g);
  hipLaunchKernelGGL(k_precompute_c, dim3(256, 2), dim3(256), 0, stream,
                     widx, embW, Wc, bc, pre_c);
  hipLaunchKernelGGL(k_gru_init, dim3(64), dim3(256), 0, stream, enc, HBT, RHT,
                     (uint4*)AT, pool);
  hipLaunchKernelGGL(k_fused, dim3(512), dim3(512), 0, stream,
                     num_words, Wg2, Wc2, pre_g, pre_c, RHT, HBT, AT,
                     WoutT, bout, out, pool);
}

// Round 11
// 392.305 us; speedup vs baseline: 3.6746x; 2.1537x over previous
//
#include <hip/hip_runtime.h>
#include <hip/hip_bf16.h>

#define V_ 32000
#define D_ 256
#define H_ 512
#define B_ 32
#define T_ 64
#define NSL 8   // column slices per batch; GRU grid = 32*NSL = 256

typedef __attribute__((ext_vector_type(8))) __bf16 bf16x8;
typedef __attribute__((ext_vector_type(4))) float f32x4;
typedef _Float16 f16x2 __attribute__((ext_vector_type(2)));
typedef unsigned int u32t;
typedef unsigned short u16t;
typedef unsigned long long u64t;

__device__ __forceinline__ u32t pack_h16(float a, float b) {
  union { _Float16 h; unsigned short u; } lo, hi;
  lo.h = (_Float16)a; hi.h = (_Float16)b;
  return (u32t)lo.u | ((u32t)hi.u << 16);
}

__device__ __forceinline__ float f16u_to_f(u16t u) {
  union { _Float16 h; unsigned short u; } x;
  x.u = u;
  return (float)x.h;
}

__device__ __forceinline__ float dot2(u32t w, u32t h, float acc) {
#if __has_builtin(__builtin_amdgcn_fdot2)
  return __builtin_amdgcn_fdot2(__builtin_bit_cast(f16x2, w),
                                __builtin_bit_cast(f16x2, h), acc, false);
#else
  f16x2 a = __builtin_bit_cast(f16x2, w);
  f16x2 b = __builtin_bit_cast(f16x2, h);
  return acc + (float)a.x * (float)b.x + (float)a.y * (float)b.y;
#endif
}

__device__ __forceinline__ void gld_lds16(const void* g, void* l) {
  __builtin_amdgcn_global_load_lds((const __attribute__((address_space(1))) void*)g,
                                   (__attribute__((address_space(3))) void*)l,
                                   16, 0, 0);
}

__device__ __forceinline__ u32t ld_rlx(const u32t* p) {
  return __hip_atomic_load(p, __ATOMIC_RELAXED, __HIP_MEMORY_SCOPE_AGENT);
}
__device__ __forceinline__ void st_rlx(u32t* p, u32t v) {
  __hip_atomic_store(p, v, __ATOMIC_RELAXED, __HIP_MEMORY_SCOPE_AGENT);
}

// ---------------- Wout [512][32000] f32 -> WoutT [32000][512] bf16 ----------------
__global__ __launch_bounds__(256) void k_transpose(const float* __restrict__ Wout,
                                                   __hip_bfloat16* __restrict__ WoutT) {
  __shared__ float tile[64][65];
  int v0 = blockIdx.x * 64;
  int h0 = blockIdx.y * 64;
  int tid = threadIdx.x;
#pragma unroll
  for (int i = 0; i < 16; ++i) {
    int idx = i * 256 + tid;
    int r = idx >> 6;
    int c = idx & 63;
    tile[r][c] = Wout[(size_t)(h0 + r) * V_ + v0 + c];
  }
  __syncthreads();
#pragma unroll
  for (int i = 0; i < 16; ++i) {
    int idx = i * 256 + tid;
    int rv = idx >> 6;
    int ch = idx & 63;
    WoutT[(size_t)(v0 + rv) * H_ + h0 + ch] = __float2bfloat16(tile[ch][rv]);
  }
}

// ---------------- merged prep: weight packs + tagged-state init ----------------
// blocks 0..255: Wg pack; 256..383: Wc pack; 384..447: HBT/RHT init.
__global__ __launch_bounds__(256) void k_prep(const float* __restrict__ Wg,
                                              const float* __restrict__ Wc,
                                              const float* __restrict__ enc,
                                              uint4* __restrict__ Wg2,
                                              uint4* __restrict__ Wc2,
                                              u32t* __restrict__ HBT,
                                              u32t* __restrict__ RHT) {
  int blk = blockIdx.x;
  int tid = threadIdx.x;
  if (blk < 256) {
    int gid = blk * 256 + tid;  // 0..65535
    int ks = gid & 3;
    int cq = (gid >> 2) & 127;
    int it = (gid >> 9) & 15;
    int s = gid >> 13;
    int j = (cq < 64) ? (s * 64 + cq) : (512 + s * 64 + (cq - 64));
    int k0 = ks * 128 + it * 8;
    uint4 v;
    v.x = pack_h16(Wg[(size_t)(256 + k0 + 0) * 1024 + j], Wg[(size_t)(256 + k0 + 1) * 1024 + j]);
    v.y = pack_h16(Wg[(size_t)(256 + k0 + 2) * 1024 + j], Wg[(size_t)(256 + k0 + 3) * 1024 + j]);
    v.z = pack_h16(Wg[(size_t)(256 + k0 + 4) * 1024 + j], Wg[(size_t)(256 + k0 + 5) * 1024 + j]);
    v.w = pack_h16(Wg[(size_t)(256 + k0 + 6) * 1024 + j], Wg[(size_t)(256 + k0 + 7) * 1024 + j]);
    Wg2[gid] = v;
  } else if (blk < 384) {
    int gid = (blk - 256) * 256 + tid;  // 0..32767
    int ks8 = gid & 7;
    int cq2 = (gid >> 3) & 63;
    int it = (gid >> 9) & 7;
    int s = gid >> 12;
    int jc = s * 64 + cq2;
    int k0 = ks8 * 64 + it * 8;
    uint4 v;
    v.x = pack_h16(Wc[(size_t)(256 + k0 + 0) * 512 + jc], Wc[(size_t)(256 + k0 + 1) * 512 + jc]);
    v.y = pack_h16(Wc[(size_t)(256 + k0 + 2) * 512 + jc], Wc[(size_t)(256 + k0 + 3) * 512 + jc]);
    v.z = pack_h16(Wc[(size_t)(256 + k0 + 4) * 512 + jc], Wc[(size_t)(256 + k0 + 5) * 512 + jc]);
    v.w = pack_h16(Wc[(size_t)(256 + k0 + 6) * 512 + jc], Wc[(size_t)(256 + k0 + 7) * 512 + jc]);
    Wc2[gid] = v;
  } else {
    int gid = (blk - 384) * 256 + tid;  // 0..16383
    int b = gid >> 9, k = gid & 511;
    u32t hv = pack_h16(enc[b * H_ + k], 0.f) & 0xffffu;  // tag 0
    st_rlx(&HBT[gid], hv);
    st_rlx(&RHT[gid], 0xFFFF0000u);
  }
}

// ---------------- x-projections (merged): pre_g[n][1024], pre_c[n][512] ----------
// gridDim.y = 6: y<4 -> gate cols, y>=4 -> cand cols (block-uniform branch).
__global__ __launch_bounds__(256) void k_precompute(const int* __restrict__ widx,
                                                    const float* __restrict__ embW,
                                                    const float* __restrict__ Wg,
                                                    const float* __restrict__ bg,
                                                    const float* __restrict__ Wc,
                                                    const float* __restrict__ bc,
                                                    float* __restrict__ pre_g,
                                                    float* __restrict__ pre_c) {
  __shared__ __align__(16) float x2[D_][8];
  __shared__ int wid[8];
  int tid = threadIdx.x;
  int n0 = blockIdx.x * 8;
  if (tid < 8) wid[tid] = widx[n0 + tid];
  __syncthreads();
#pragma unroll
  for (int i = 0; i < 8; ++i)
    x2[tid][i] = embW[(size_t)wid[i] * D_ + tid];
  __syncthreads();

  float acc[8];
  if (blockIdx.y < 4) {
    int J = blockIdx.y * 256 + tid;  // 0..1023
    float bias = bg[J];
#pragma unroll
    for (int i = 0; i < 8; ++i) acc[i] = bias;
    for (int d = 0; d < D_; ++d) {
      float4 xa = *(const float4*)&x2[d][0];
      float4 xb = *(const float4*)&x2[d][4];
      float w = Wg[(size_t)d * 1024 + J];
      acc[0] = fmaf(xa.x, w, acc[0]); acc[1] = fmaf(xa.y, w, acc[1]);
      acc[2] = fmaf(xa.z, w, acc[2]); acc[3] = fmaf(xa.w, w, acc[3]);
      acc[4] = fmaf(xb.x, w, acc[4]); acc[5] = fmaf(xb.y, w, acc[5]);
      acc[6] = fmaf(xb.z, w, acc[6]); acc[7] = fmaf(xb.w, w, acc[7]);
    }
#pragma unroll
    for (int i = 0; i < 8; ++i)
      pre_g[(size_t)(n0 + i) * 1024 + J] = acc[i];
  } else {
    int Jc = (blockIdx.y - 4) * 256 + tid;  // 0..511
    float bias = bc[Jc];
#pragma unroll
    for (int i = 0; i < 8; ++i) acc[i] = bias;
    for (int d = 0; d < D_; ++d) {
      float4 xa = *(const float4*)&x2[d][0];
      float4 xb = *(const float4*)&x2[d][4];
      float w = Wc[(size_t)d * 512 + Jc];
      acc[0] = fmaf(xa.x, w, acc[0]); acc[1] = fmaf(xa.y, w, acc[1]);
      acc[2] = fmaf(xa.z, w, acc[2]); acc[3] = fmaf(xa.w, w, acc[3]);
      acc[4] = fmaf(xb.x, w, acc[4]); acc[5] = fmaf(xb.y, w, acc[5]);
      acc[6] = fmaf(xb.z, w, acc[6]); acc[7] = fmaf(xb.w, w, acc[7]);
    }
#pragma unroll
    for (int i = 0; i < 8; ++i)
      pre_c[(size_t)(n0 + i) * 512 + Jc] = acc[i];
  }
}

// ---------------- GRU v7: tag-embedded payload exchange (proven 193 us) -------------
// 256 blocks = 32 batches x 8 slices; weights register-resident; relaxed agent
// tagged stores/polls, no fences, no drains. 4-way split accumulator chains.
__global__ __launch_bounds__(512, 2) void k_gru7(const int* __restrict__ num_words,
                                                 const uint4* __restrict__ Wg2,
                                                 const uint4* __restrict__ Wc2,
                                                 const float* __restrict__ pre_g,
                                                 const float* __restrict__ pre_c,
                                                 u32t* __restrict__ RHT,
                                                 u32t* __restrict__ HBT,
                                                 u32t* __restrict__ A32) {
  __shared__ __align__(16) u32t h2_l[256];
  __shared__ __align__(16) u32t rh2_l[256];
  __shared__ float u_l[64];
  int bid = blockIdx.x;
  int b = bid & 31;
  int s = bid >> 5;
  int tid = threadIdx.x;
  int nw = num_words[b];

  int cq = tid >> 2, ks = tid & 3;
  int j1 = (cq < 64) ? (s * 64 + cq) : (512 + s * 64 + (cq - 64));
  int cq2 = tid >> 3, ks8 = tid & 7;
  int jc = s * 64 + cq2;

  uint4 wg[16];
#pragma unroll
  for (int i = 0; i < 16; ++i) {
    int ii = (i + ks) & 15;
    wg[i] = Wg2[(((size_t)s * 16 + ii) * 128 + cq) * 4 + ks];
  }
  uint4 wc[8];
#pragma unroll
  for (int i = 0; i < 8; ++i) {
    int ii = (i + ks8) & 7;
    wc[i] = Wc2[(((size_t)s * 8 + ii) * 64 + cq2) * 8 + ks8];
  }

  u32t* HBp = HBT + (size_t)b * 512;
  u32t* RHp = RHT + (size_t)b * 512;
  bool pub1 = (ks == 0) && (cq < 64);
  bool ulane = (ks == 0) && (cq >= 64);
  bool pub2 = (ks8 == 0);
  bool writer2 = pub2 && ((cq2 & 1) == 0);

  for (int t = 0; t < T_; ++t) {
    float pg = pre_g[((size_t)b * T_ + t) * 1024 + j1];
    float pc = pre_c[((size_t)b * T_ + t) * 512 + jc];

    __syncthreads();
    {
      u32t want = (u32t)t << 16;
      u32t v;
      do { v = ld_rlx(&HBp[tid]); } while ((v & 0xffff0000u) != want);
      ((volatile u16t*)h2_l)[tid] = (u16t)v;
    }
    __syncthreads();

    // ---- phase 1: gates (4-way split accumulators) ----
    float a0 = 0.f, a1 = 0.f, a2s = 0.f, a3 = 0.f;
    const uint4* h4 = (const uint4*)h2_l;
#pragma unroll
    for (int i = 0; i < 16; ++i) {
      int ii = (i + ks) & 15;
      uint4 hv = h4[ks * 16 + ii];
      a0 = dot2(wg[i].x, hv.x, a0);
      a1 = dot2(wg[i].y, hv.y, a1);
      a2s = dot2(wg[i].z, hv.z, a2s);
      a3 = dot2(wg[i].w, hv.w, a3);
    }
    float a = (a0 + a1) + (a2s + a3);
    a += __shfl_xor(a, 1);
    a += __shfl_xor(a, 2);
    float gate = 1.f / (1.f + __expf(-(a + pg)));
    if (cq < 64) {
      float hh = f16u_to_f(((const u16t*)h2_l)[s * 64 + cq]);
      if (pub1)
        st_rlx(&RHp[s * 64 + cq],
               (pack_h16(gate * hh, 0.f) & 0xffffu) | ((u32t)(t + 1) << 16));
    } else if (ulane) {
      u_l[cq - 64] = gate;
    }

    {
      u32t want = (u32t)(t + 1) << 16;
      u32t v;
      do { v = ld_rlx(&RHp[tid]); } while ((v & 0xffff0000u) != want);
      ((volatile u16t*)rh2_l)[tid] = (u16t)v;
    }
    __syncthreads();

    // ---- phase 2: candidate + state update (4-way split accumulators) ----
    float c0 = 0.f, c1 = 0.f, c2 = 0.f, c3 = 0.f;
    const uint4* r4 = (const uint4*)rh2_l;
#pragma unroll
    for (int i = 0; i < 8; ++i) {
      int ii = (i + ks8) & 7;
      uint4 rv = r4[ks8 * 8 + ii];
      c0 = dot2(wc[i].x, rv.x, c0);
      c1 = dot2(wc[i].y, rv.y, c1);
      c2 = dot2(wc[i].z, rv.z, c2);
      c3 = dot2(wc[i].w, rv.w, c3);
    }
    float a2 = (c0 + c1) + (c2 + c3);
    a2 += __shfl_xor(a2, 1);
    a2 += __shfl_xor(a2, 2);
    a2 += __shfl_xor(a2, 4);
    float cv = tanhf(a2 + pc);
    float uu = u_l[cq2];
    float hold = f16u_to_f(((const u16t*)h2_l)[jc]);
    float hn = uu * hold + (1.f - uu) * cv;
    bool live = t < nw;
    float hnext = live ? hn : hold;
    if (pub2)
      st_rlx(&HBp[s * 64 + cq2],
             (pack_h16(hnext, 0.f) & 0xffffu) | ((u32t)(t + 1) << 16));
    u32t ma = (u32t)__hip_bfloat16_raw(__float2bfloat16(live ? hn : 0.f)).x;
    u32t oa = (u32t)__shfl_xor((int)ma, 8);
    if (writer2)
      A32[(((size_t)b * T_ + t) * 512 + jc) >> 1] = ma | (oa << 16);
  }
}

// ---------------- projection: C[2048][32000] = A[2048][512] @ WoutT^T + bout -------
// MFMA operands SWAPPED (mfma(b_frag, a_frag)): lane holds 4 consecutive C-columns
// of one row -> f32x4 accumulator stores directly as one dwordx4 (16 stores vs 64).
__global__ __launch_bounds__(256) void k_proj(const __hip_bfloat16* __restrict__ Ap,
                                              const __hip_bfloat16* __restrict__ BTp,
                                              const float* __restrict__ bout,
                                              float* __restrict__ C) {
  __shared__ char As[128 * 64 * 2];
  __shared__ char Bs[128 * 64 * 2];
  int tid = threadIdx.x;
  int lane = tid & 63;
  int wave = tid >> 6;
  int m0 = blockIdx.x * 128;
  int n0 = blockIdx.y * 128;
  int wm = wave >> 1, wn = wave & 1;
  f32x4 acc[4][4] = {};

  const char* Ab = (const char*)Ap;
  const char* Bb = (const char*)BTp;

  for (int ks = 0; ks < 8; ++ks) {
    int k0 = ks * 64;
    __syncthreads();
#pragma unroll
    for (int inst = 0; inst < 4; ++inst) {
      int o = inst * 4096 + wave * 1024;
      int ol = o + lane * 16;
      int r = ol >> 7;
      int cb = ol & 127;
      gld_lds16(Ab + ((size_t)(m0 + r) * 512 + k0) * 2 + cb, As + o);
      gld_lds16(Bb + ((size_t)(n0 + r) * 512 + k0) * 2 + cb, Bs + o);
    }
    __syncthreads();
#pragma unroll
    for (int kk = 0; kk < 64; kk += 32) {
      bf16x8 af[4], bfr[4];
      int cbyte = kk * 2 + ((lane >> 4) << 4);
#pragma unroll
      for (int mi = 0; mi < 4; ++mi) {
        int row = wm * 64 + mi * 16 + (lane & 15);
        af[mi] = *(const bf16x8*)(As + row * 128 + cbyte);
      }
#pragma unroll
      for (int ni = 0; ni < 4; ++ni) {
        int row = wn * 64 + ni * 16 + (lane & 15);
        bfr[ni] = *(const bf16x8*)(Bs + row * 128 + cbyte);
      }
#pragma unroll
      for (int mi = 0; mi < 4; ++mi)
#pragma unroll
        for (int ni = 0; ni < 4; ++ni)
          acc[mi][ni] = __builtin_amdgcn_mfma_f32_16x16x32_bf16(bfr[ni], af[mi], acc[mi][ni], 0, 0, 0);
    }
  }
  // epilogue (swapped layout): D'[row=(lane>>4)*4+reg -> n][col=lane&15 -> m]
  // lane stores float4 of 4 consecutive cols for its row.
#pragma unroll
  for (int ni = 0; ni < 4; ++ni) {
    int colbase = n0 + wn * 64 + ni * 16 + ((lane >> 4) << 2);
    float4 bb = *(const float4*)&bout[colbase];
#pragma unroll
    for (int mi = 0; mi < 4; ++mi) {
      int row = m0 + wm * 64 + mi * 16 + (lane & 15);
      float4 v;
      v.x = acc[mi][ni][0] + bb.x;
      v.y = acc[mi][ni][1] + bb.y;
      v.z = acc[mi][ni][2] + bb.z;
      v.w = acc[mi][ni][3] + bb.w;
      *(float4*)&C[(size_t)row * V_ + colbase] = v;
    }
  }
}

extern "C" void kernel_launch(void* const* d_in, const int* in_sizes, int n_in,
                              void* d_out, int out_size, void* d_ws, size_t ws_size,
                              hipStream_t stream) {
  const int* widx = (const int*)d_in[0];
  const int* num_words = (const int*)d_in[1];
  const float* enc = (const float*)d_in[2];
  const float* embW = (const float*)d_in[3];
  const float* Wg = (const float*)d_in[4];
  const float* bg = (const float*)d_in[5];
  const float* Wc = (const float*)d_in[6];
  const float* bc = (const float*)d_in[7];
  const float* Wout = (const float*)d_in[8];
  const float* bout = (const float*)d_in[9];
  float* out = (float*)d_out;

  char* ws = (char*)d_ws;
  float* pre_g = (float*)(ws);                              // 8,388,608
  float* pre_c = (float*)(ws + 8388608);                    // 4,194,304
  __hip_bfloat16* A = (__hip_bfloat16*)(ws + 12582912);     // 2,097,152
  __hip_bfloat16* WoutT = (__hip_bfloat16*)(ws + 14680064); // 32,768,000
  uint4* Wg2 = (uint4*)(ws + 47448064);                     // 1,048,576
  uint4* Wc2 = (uint4*)(ws + 48496640);                     //   524,288
  u32t* RHT = (u32t*)(ws + 49020928);                       //    65,536
  u32t* HBT = (u32t*)(ws + 49086464);                       //    65,536

  hipLaunchKernelGGL(k_prep, dim3(448), dim3(256), 0, stream,
                     Wg, Wc, enc, Wg2, Wc2, HBT, RHT);
  hipLaunchKernelGGL(k_transpose, dim3(500, 8), dim3(256), 0, stream, Wout, WoutT);
  hipLaunchKernelGGL(k_precompute, dim3(256, 6), dim3(256), 0, stream,
                     widx, embW, Wg, bg, Wc, bc, pre_g, pre_c);
  hipLaunchKernelGGL(k_gru7, dim3(32 * NSL), dim3(512), 0, stream,
                     num_words, Wg2, Wc2, pre_g, pre_c, RHT, HBT, (u32t*)A);
  hipLaunchKernelGGL(k_proj, dim3(16, 250), dim3(256), 0, stream, A, WoutT, bout, out);
}

// Round 13
// 383.677 us; speedup vs baseline: 3.7573x; 1.0225x over previous
//
#include <hip/hip_runtime.h>
#include <hip/hip_bf16.h>

#define V_ 32000
#define D_ 256
#define H_ 512
#define B_ 32
#define T_ 64
#define NSL 8   // column slices per batch; GRU grid = 32*NSL = 256

typedef __attribute__((ext_vector_type(8))) __bf16 bf16x8;
typedef __attribute__((ext_vector_type(4))) float f32x4;
typedef _Float16 f16x2 __attribute__((ext_vector_type(2)));
typedef unsigned int u32t;
typedef unsigned short u16t;
typedef unsigned long long u64t;

__device__ __forceinline__ u32t pack_h16(float a, float b) {
  union { _Float16 h; unsigned short u; } lo, hi;
  lo.h = (_Float16)a; hi.h = (_Float16)b;
  return (u32t)lo.u | ((u32t)hi.u << 16);
}

__device__ __forceinline__ float f16u_to_f(u16t u) {
  union { _Float16 h; unsigned short u; } x;
  x.u = u;
  return (float)x.h;
}

__device__ __forceinline__ float dot2(u32t w, u32t h, float acc) {
#if __has_builtin(__builtin_amdgcn_fdot2)
  return __builtin_amdgcn_fdot2(__builtin_bit_cast(f16x2, w),
                                __builtin_bit_cast(f16x2, h), acc, false);
#else
  f16x2 a = __builtin_bit_cast(f16x2, w);
  f16x2 b = __builtin_bit_cast(f16x2, h);
  return acc + (float)a.x * (float)b.x + (float)a.y * (float)b.y;
#endif
}

__device__ __forceinline__ void gld_lds16(const void* g, void* l) {
  __builtin_amdgcn_global_load_lds((const __attribute__((address_space(1))) void*)g,
                                   (__attribute__((address_space(3))) void*)l,
                                   16, 0, 0);
}

__device__ __forceinline__ u32t ld_rlx(const u32t* p) {
  return __hip_atomic_load(p, __ATOMIC_RELAXED, __HIP_MEMORY_SCOPE_AGENT);
}
__device__ __forceinline__ void st_rlx(u32t* p, u32t v) {
  __hip_atomic_store(p, v, __ATOMIC_RELAXED, __HIP_MEMORY_SCOPE_AGENT);
}

// ---------------- merged setup: transpose + weight packs/init + x-projections -------
// blocks [0,4000):      Wout -> WoutT transpose (500 x 8 tile grid)
// blocks [4000,4448):   Wg/Wc f16 packs + tagged HBT/RHT init
// blocks [4448,5984):   pre_g / pre_c x-projections (256 x 6)
__global__ __launch_bounds__(256) void k_setup(const float* __restrict__ Wout,
                                               __hip_bfloat16* __restrict__ WoutT,
                                               const float* __restrict__ Wg,
                                               const float* __restrict__ Wc,
                                               const float* __restrict__ enc,
                                               uint4* __restrict__ Wg2,
                                               uint4* __restrict__ Wc2,
                                               u32t* __restrict__ HBT,
                                               u32t* __restrict__ RHT,
                                               const int* __restrict__ widx,
                                               const float* __restrict__ embW,
                                               const float* __restrict__ bg,
                                               const float* __restrict__ bc,
                                               float* __restrict__ pre_g,
                                               float* __restrict__ pre_c) {
  int blk = blockIdx.x;
  int tid = threadIdx.x;

  if (blk < 4000) {
    // ---------- transpose ----------
    __shared__ float tile[64][65];
    int v0 = (blk % 500) * 64;
    int h0 = (blk / 500) * 64;
#pragma unroll
    for (int i = 0; i < 16; ++i) {
      int idx = i * 256 + tid;
      int r = idx >> 6;
      int c = idx & 63;
      tile[r][c] = Wout[(size_t)(h0 + r) * V_ + v0 + c];
    }
    __syncthreads();
#pragma unroll
    for (int i = 0; i < 16; ++i) {
      int idx = i * 256 + tid;
      int rv = idx >> 6;
      int ch = idx & 63;
      WoutT[(size_t)(v0 + rv) * H_ + h0 + ch] = __float2bfloat16(tile[ch][rv]);
    }
  } else if (blk < 4448) {
    // ---------- packs + init ----------
    int pblk = blk - 4000;
    if (pblk < 256) {
      int gid = pblk * 256 + tid;  // 0..65535
      int ks = gid & 3;
      int cq = (gid >> 2) & 127;
      int it = (gid >> 9) & 15;
      int s = gid >> 13;
      int j = (cq < 64) ? (s * 64 + cq) : (512 + s * 64 + (cq - 64));
      int k0 = ks * 128 + it * 8;
      uint4 v;
      v.x = pack_h16(Wg[(size_t)(256 + k0 + 0) * 1024 + j], Wg[(size_t)(256 + k0 + 1) * 1024 + j]);
      v.y = pack_h16(Wg[(size_t)(256 + k0 + 2) * 1024 + j], Wg[(size_t)(256 + k0 + 3) * 1024 + j]);
      v.z = pack_h16(Wg[(size_t)(256 + k0 + 4) * 1024 + j], Wg[(size_t)(256 + k0 + 5) * 1024 + j]);
      v.w = pack_h16(Wg[(size_t)(256 + k0 + 6) * 1024 + j], Wg[(size_t)(256 + k0 + 7) * 1024 + j]);
      Wg2[gid] = v;
    } else if (pblk < 384) {
      int gid = (pblk - 256) * 256 + tid;  // 0..32767
      int ks8 = gid & 7;
      int cq2 = (gid >> 3) & 63;
      int it = (gid >> 9) & 7;
      int s = gid >> 12;
      int jc = s * 64 + cq2;
      int k0 = ks8 * 64 + it * 8;
      uint4 v;
      v.x = pack_h16(Wc[(size_t)(256 + k0 + 0) * 512 + jc], Wc[(size_t)(256 + k0 + 1) * 512 + jc]);
      v.y = pack_h16(Wc[(size_t)(256 + k0 + 2) * 512 + jc], Wc[(size_t)(256 + k0 + 3) * 512 + jc]);
      v.z = pack_h16(Wc[(size_t)(256 + k0 + 4) * 512 + jc], Wc[(size_t)(256 + k0 + 5) * 512 + jc]);
      v.w = pack_h16(Wc[(size_t)(256 + k0 + 6) * 512 + jc], Wc[(size_t)(256 + k0 + 7) * 512 + jc]);
      Wc2[gid] = v;
    } else {
      int gid = (pblk - 384) * 256 + tid;  // 0..16383
      int b = gid >> 9, k = gid & 511;
      u32t hv = pack_h16(enc[b * H_ + k], 0.f) & 0xffffu;  // tag 0
      st_rlx(&HBT[gid], hv);
      st_rlx(&RHT[gid], 0xFFFF0000u);
    }
  } else {
    // ---------- x-projections ----------
    __shared__ __align__(16) float x2[D_][8];
    __shared__ int wid[8];
    int idx = blk - 4448;          // 0..1535
    int bx = idx & 255;            // token group
    int by = idx >> 8;             // 0..5
    int n0 = bx * 8;
    if (tid < 8) wid[tid] = widx[n0 + tid];
    __syncthreads();
#pragma unroll
    for (int i = 0; i < 8; ++i)
      x2[tid][i] = embW[(size_t)wid[i] * D_ + tid];
    __syncthreads();

    float acc[8];
    if (by < 4) {
      int J = by * 256 + tid;  // 0..1023
      float bias = bg[J];
#pragma unroll
      for (int i = 0; i < 8; ++i) acc[i] = bias;
      for (int d = 0; d < D_; ++d) {
        float4 xa = *(const float4*)&x2[d][0];
        float4 xb = *(const float4*)&x2[d][4];
        float w = Wg[(size_t)d * 1024 + J];
        acc[0] = fmaf(xa.x, w, acc[0]); acc[1] = fmaf(xa.y, w, acc[1]);
        acc[2] = fmaf(xa.z, w, acc[2]); acc[3] = fmaf(xa.w, w, acc[3]);
        acc[4] = fmaf(xb.x, w, acc[4]); acc[5] = fmaf(xb.y, w, acc[5]);
        acc[6] = fmaf(xb.z, w, acc[6]); acc[7] = fmaf(xb.w, w, acc[7]);
      }
#pragma unroll
      for (int i = 0; i < 8; ++i)
        pre_g[(size_t)(n0 + i) * 1024 + J] = acc[i];
    } else {
      int Jc = (by - 4) * 256 + tid;  // 0..511
      float bias = bc[Jc];
#pragma unroll
      for (int i = 0; i < 8; ++i) acc[i] = bias;
      for (int d = 0; d < D_; ++d) {
        float4 xa = *(const float4*)&x2[d][0];
        float4 xb = *(const float4*)&x2[d][4];
        float w = Wc[(size_t)d * 512 + Jc];
        acc[0] = fmaf(xa.x, w, acc[0]); acc[1] = fmaf(xa.y, w, acc[1]);
        acc[2] = fmaf(xa.z, w, acc[2]); acc[3] = fmaf(xa.w, w, acc[3]);
        acc[4] = fmaf(xb.x, w, acc[4]); acc[5] = fmaf(xb.y, w, acc[5]);
        acc[6] = fmaf(xb.z, w, acc[6]); acc[7] = fmaf(xb.w, w, acc[7]);
      }
#pragma unroll
      for (int i = 0; i < 8; ++i)
        pre_c[(size_t)(n0 + i) * 512 + Jc] = acc[i];
    }
  }
}

// ---------------- GRU v7: tag-embedded payload exchange (proven ~193 us) ------------
__global__ __launch_bounds__(512, 2) void k_gru7(const int* __restrict__ num_words,
                                                 const uint4* __restrict__ Wg2,
                                                 const uint4* __restrict__ Wc2,
                                                 const float* __restrict__ pre_g,
                                                 const float* __restrict__ pre_c,
                                                 u32t* __restrict__ RHT,
                                                 u32t* __restrict__ HBT,
                                                 u32t* __restrict__ A32) {
  __shared__ __align__(16) u32t h2_l[256];
  __shared__ __align__(16) u32t rh2_l[256];
  __shared__ float u_l[64];
  int bid = blockIdx.x;
  int b = bid & 31;
  int s = bid >> 5;
  int tid = threadIdx.x;
  int nw = num_words[b];

  int cq = tid >> 2, ks = tid & 3;
  int j1 = (cq < 64) ? (s * 64 + cq) : (512 + s * 64 + (cq - 64));
  int cq2 = tid >> 3, ks8 = tid & 7;
  int jc = s * 64 + cq2;

  uint4 wg[16];
#pragma unroll
  for (int i = 0; i < 16; ++i) {
    int ii = (i + ks) & 15;
    wg[i] = Wg2[(((size_t)s * 16 + ii) * 128 + cq) * 4 + ks];
  }
  uint4 wc[8];
#pragma unroll
  for (int i = 0; i < 8; ++i) {
    int ii = (i + ks8) & 7;
    wc[i] = Wc2[(((size_t)s * 8 + ii) * 64 + cq2) * 8 + ks8];
  }

  u32t* HBp = HBT + (size_t)b * 512;
  u32t* RHp = RHT + (size_t)b * 512;
  bool pub1 = (ks == 0) && (cq < 64);
  bool ulane = (ks == 0) && (cq >= 64);
  bool pub2 = (ks8 == 0);
  bool writer2 = pub2 && ((cq2 & 1) == 0);

  for (int t = 0; t < T_; ++t) {
    float pg = pre_g[((size_t)b * T_ + t) * 1024 + j1];
    float pc = pre_c[((size_t)b * T_ + t) * 512 + jc];

    __syncthreads();
    {
      u32t want = (u32t)t << 16;
      u32t v;
      do { v = ld_rlx(&HBp[tid]); } while ((v & 0xffff0000u) != want);
      ((volatile u16t*)h2_l)[tid] = (u16t)v;
    }
    __syncthreads();

    // ---- phase 1: gates (4-way split accumulators) ----
    float a0 = 0.f, a1 = 0.f, a2s = 0.f, a3 = 0.f;
    const uint4* h4 = (const uint4*)h2_l;
#pragma unroll
    for (int i = 0; i < 16; ++i) {
      int ii = (i + ks) & 15;
      uint4 hv = h4[ks * 16 + ii];
      a0 = dot2(wg[i].x, hv.x, a0);
      a1 = dot2(wg[i].y, hv.y, a1);
      a2s = dot2(wg[i].z, hv.z, a2s);
      a3 = dot2(wg[i].w, hv.w, a3);
    }
    float a = (a0 + a1) + (a2s + a3);
    a += __shfl_xor(a, 1);
    a += __shfl_xor(a, 2);
    float gate = 1.f / (1.f + __expf(-(a + pg)));
    if (cq < 64) {
      float hh = f16u_to_f(((const u16t*)h2_l)[s * 64 + cq]);
      if (pub1)
        st_rlx(&RHp[s * 64 + cq],
               (pack_h16(gate * hh, 0.f) & 0xffffu) | ((u32t)(t + 1) << 16));
    } else if (ulane) {
      u_l[cq - 64] = gate;
    }

    {
      u32t want = (u32t)(t + 1) << 16;
      u32t v;
      do { v = ld_rlx(&RHp[tid]); } while ((v & 0xffff0000u) != want);
      ((volatile u16t*)rh2_l)[tid] = (u16t)v;
    }
    __syncthreads();

    // ---- phase 2: candidate + state update (4-way split accumulators) ----
    float c0 = 0.f, c1 = 0.f, c2 = 0.f, c3 = 0.f;
    const uint4* r4 = (const uint4*)rh2_l;
#pragma unroll
    for (int i = 0; i < 8; ++i) {
      int ii = (i + ks8) & 7;
      uint4 rv = r4[ks8 * 8 + ii];
      c0 = dot2(wc[i].x, rv.x, c0);
      c1 = dot2(wc[i].y, rv.y, c1);
      c2 = dot2(wc[i].z, rv.z, c2);
      c3 = dot2(wc[i].w, rv.w, c3);
    }
    float a2 = (c0 + c1) + (c2 + c3);
    a2 += __shfl_xor(a2, 1);
    a2 += __shfl_xor(a2, 2);
    a2 += __shfl_xor(a2, 4);
    float cv = tanhf(a2 + pc);
    float uu = u_l[cq2];
    float hold = f16u_to_f(((const u16t*)h2_l)[jc]);
    float hn = uu * hold + (1.f - uu) * cv;
    bool live = t < nw;
    float hnext = live ? hn : hold;
    if (pub2)
      st_rlx(&HBp[s * 64 + cq2],
             (pack_h16(hnext, 0.f) & 0xffffu) | ((u32t)(t + 1) << 16));
    u32t ma = (u32t)__hip_bfloat16_raw(__float2bfloat16(live ? hn : 0.f)).x;
    u32t oa = (u32t)__shfl_xor((int)ma, 8);
    if (writer2)
      A32[(((size_t)b * T_ + t) * 512 + jc) >> 1] = ma | (oa << 16);
  }
}

// ---------------- projection: C[2048][32000] = A[2048][512] @ WoutT^T + bout -------
// Swapped MFMA operands: lane holds 4 consecutive C columns -> one dwordx4 NT store.
__global__ __launch_bounds__(256) void k_proj(const __hip_bfloat16* __restrict__ Ap,
                                              const __hip_bfloat16* __restrict__ BTp,
                                              const float* __restrict__ bout,
                                              float* __restrict__ C) {
  __shared__ char As[128 * 64 * 2];
  __shared__ char Bs[128 * 64 * 2];
  int tid = threadIdx.x;
  int lane = tid & 63;
  int wave = tid >> 6;
  int m0 = blockIdx.x * 128;
  int n0 = blockIdx.y * 128;
  int wm = wave >> 1, wn = wave & 1;
  f32x4 acc[4][4] = {};

  const char* Ab = (const char*)Ap;
  const char* Bb = (const char*)BTp;

  for (int ks = 0; ks < 8; ++ks) {
    int k0 = ks * 64;
    __syncthreads();
#pragma unroll
    for (int inst = 0; inst < 4; ++inst) {
      int o = inst * 4096 + wave * 1024;
      int ol = o + lane * 16;
      int r = ol >> 7;
      int cb = ol & 127;
      gld_lds16(Ab + ((size_t)(m0 + r) * 512 + k0) * 2 + cb, As + o);
      gld_lds16(Bb + ((size_t)(n0 + r) * 512 + k0) * 2 + cb, Bs + o);
    }
    __syncthreads();
#pragma unroll
    for (int kk = 0; kk < 64; kk += 32) {
      bf16x8 af[4], bfr[4];
      int cbyte = kk * 2 + ((lane >> 4) << 4);
#pragma unroll
      for (int mi = 0; mi < 4; ++mi) {
        int row = wm * 64 + mi * 16 + (lane & 15);
        af[mi] = *(const bf16x8*)(As + row * 128 + cbyte);
      }
#pragma unroll
      for (int ni = 0; ni < 4; ++ni) {
        int row = wn * 64 + ni * 16 + (lane & 15);
        bfr[ni] = *(const bf16x8*)(Bs + row * 128 + cbyte);
      }
#pragma unroll
      for (int mi = 0; mi < 4; ++mi)
#pragma unroll
        for (int ni = 0; ni < 4; ++ni)
          acc[mi][ni] = __builtin_amdgcn_mfma_f32_16x16x32_bf16(bfr[ni], af[mi], acc[mi][ni], 0, 0, 0);
    }
  }
  // epilogue (swapped layout): lane stores f32x4 of 4 consecutive cols per row.
  // Nontemporal: keep the 262MB C stream from evicting WoutT.
#pragma unroll
  for (int ni = 0; ni < 4; ++ni) {
    int colbase = n0 + wn * 64 + ni * 16 + ((lane >> 4) << 2);
    float4 bb = *(const float4*)&bout[colbase];
#pragma unroll
    for (int mi = 0; mi < 4; ++mi) {
      int row = m0 + wm * 64 + mi * 16 + (lane & 15);
      f32x4 v;
      v.x = acc[mi][ni][0] + bb.x;
      v.y = acc[mi][ni][1] + bb.y;
      v.z = acc[mi][ni][2] + bb.z;
      v.w = acc[mi][ni][3] + bb.w;
      __builtin_nontemporal_store(v, (f32x4*)&C[(size_t)row * V_ + colbase]);
    }
  }
}

extern "C" void kernel_launch(void* const* d_in, const int* in_sizes, int n_in,
                              void* d_out, int out_size, void* d_ws, size_t ws_size,
                              hipStream_t stream) {
  const int* widx = (const int*)d_in[0];
  const int* num_words = (const int*)d_in[1];
  const float* enc = (const float*)d_in[2];
  const float* embW = (const float*)d_in[3];
  const float* Wg = (const float*)d_in[4];
  const float* bg = (const float*)d_in[5];
  const float* Wc = (const float*)d_in[6];
  const float* bc = (const float*)d_in[7];
  const float* Wout = (const float*)d_in[8];
  const float* bout = (const float*)d_in[9];
  float* out = (float*)d_out;

  char* ws = (char*)d_ws;
  float* pre_g = (float*)(ws);                              // 8,388,608
  float* pre_c = (float*)(ws + 8388608);                    // 4,194,304
  __hip_bfloat16* A = (__hip_bfloat16*)(ws + 12582912);     // 2,097,152
  __hip_bfloat16* WoutT = (__hip_bfloat16*)(ws + 14680064); // 32,768,000
  uint4* Wg2 = (uint4*)(ws + 47448064);                     // 1,048,576
  uint4* Wc2 = (uint4*)(ws + 48496640);                     //   524,288
  u32t* RHT = (u32t*)(ws + 49020928);                       //    65,536
  u32t* HBT = (u32t*)(ws + 49086464);                       //    65,536

  hipLaunchKernelGGL(k_setup, dim3(5984), dim3(256), 0, stream,
                     Wout, WoutT, Wg, Wc, enc, Wg2, Wc2, HBT, RHT,
                     widx, embW, bg, bc, pre_g, pre_c);
  hipLaunchKernelGGL(k_gru7, dim3(32 * NSL), dim3(512), 0, stream,
                     num_words, Wg2, Wc2, pre_g, pre_c, RHT, HBT, (u32t*)A);
  hipLaunchKernelGGL(k_proj, dim3(16, 250), dim3(256), 0, stream, A, WoutT, bout, out);
}